// Round 1
// baseline (2183.017 us; speedup 1.0000x reference)
//
#include <hip/hip_runtime.h>
#include <hip/hip_bf16.h>

#define DIMSZ 1024
#define HEADS 16
#define HEAD_DIM 64
#define BATCH 2
#define SEQ 2048

// ---------------------------------------------------------------------------
// Shared fp32 GEMM mainloop: C_tile(64x64) = A(m0.., K) @ B(.., n0..)
// 256 threads, 4x4 microtile per thread. K must be a multiple of 16.
// ---------------------------------------------------------------------------
__device__ __forceinline__ void gemm_mainloop(const float* __restrict__ A, int lda,
                                              const float* __restrict__ Bm, int ldb,
                                              int m0, int n0, int K,
                                              float acc[4][4],
                                              float (*As)[68], float (*Bs)[68]) {
  const int tid = threadIdx.x;
  const int tx = tid & 15, ty = tid >> 4;
  const int am = tid >> 2;            // 0..63  (A row within tile)
  const int ak = (tid & 3) * 4;       // 0,4,8,12
  const int bk = tid >> 4;            // 0..15  (B row within k-tile)
  const int bn = (tid & 15) * 4;      // 0..60

  for (int k0 = 0; k0 < K; k0 += 16) {
    const float4 a4 = *reinterpret_cast<const float4*>(&A[(size_t)(m0 + am) * lda + k0 + ak]);
    const float4 b4 = *reinterpret_cast<const float4*>(&Bm[(size_t)(k0 + bk) * ldb + n0 + bn]);
    __syncthreads();   // previous tile's compute done before overwrite
    As[ak + 0][am] = a4.x;
    As[ak + 1][am] = a4.y;
    As[ak + 2][am] = a4.z;
    As[ak + 3][am] = a4.w;
    *reinterpret_cast<float4*>(&Bs[bk][bn]) = b4;
    __syncthreads();
#pragma unroll
    for (int kk = 0; kk < 16; ++kk) {
      const float4 av = *reinterpret_cast<const float4*>(&As[kk][ty * 4]);
      const float4 bv = *reinterpret_cast<const float4*>(&Bs[kk][tx * 4]);
      const float a[4] = {av.x, av.y, av.z, av.w};
      const float b[4] = {bv.x, bv.y, bv.z, bv.w};
#pragma unroll
      for (int i = 0; i < 4; ++i)
#pragma unroll
        for (int j = 0; j < 4; ++j)
          acc[i][j] = fmaf(a[i], b[j], acc[i][j]);
    }
  }
}

// ---------------------------------------------------------------------------
// Kernel 1: qkv = x @ Wqkv, scattered into q/k/v buffers laid out [B,H,T,Dh]
// ---------------------------------------------------------------------------
__global__ __launch_bounds__(256) void k_gemm_qkv(const float* __restrict__ X,
                                                  const float* __restrict__ W,
                                                  float* __restrict__ qb,
                                                  float* __restrict__ kb,
                                                  float* __restrict__ vb) {
  __shared__ __align__(16) float As[16][68];
  __shared__ __align__(16) float Bs[16][68];
  float acc[4][4] = {};
  const int n0 = blockIdx.x * 64;   // N = 3072
  const int m0 = blockIdx.y * 64;   // M = 4096
  gemm_mainloop(X, DIMSZ, W, 3 * DIMSZ, m0, n0, DIMSZ, acc, As, Bs);

  const int tx = threadIdx.x & 15, ty = threadIdx.x >> 4;
  const int comp = n0 >> 10;            // 0:q 1:k 2:v   (tile never crosses)
  const int h = (n0 >> 6) & 15;
  const int b = m0 >> 11;
  float* dst = (comp == 0) ? qb : (comp == 1 ? kb : vb);
#pragma unroll
  for (int i = 0; i < 4; ++i) {
    const int t = (m0 & (SEQ - 1)) + ty * 4 + i;
    const float4 o = make_float4(acc[i][0], acc[i][1], acc[i][2], acc[i][3]);
    *reinterpret_cast<float4*>(&dst[(((size_t)(b * HEADS + h)) * SEQ + t) * HEAD_DIM + tx * 4]) = o;
  }
}

// ---------------------------------------------------------------------------
// Kernel 2: r_h = r @ Wr, stored REVERSED:  rr[h][rel][d] = r_h[T-1-rel][h][d]
// ---------------------------------------------------------------------------
__global__ __launch_bounds__(256) void k_gemm_r(const float* __restrict__ R,
                                                const float* __restrict__ Wr,
                                                float* __restrict__ rrb) {
  __shared__ __align__(16) float As[16][68];
  __shared__ __align__(16) float Bs[16][68];
  float acc[4][4] = {};
  const int n0 = blockIdx.x * 64;   // N = 1024
  const int m0 = blockIdx.y * 64;   // M = 2048
  gemm_mainloop(R, DIMSZ, Wr, DIMSZ, m0, n0, DIMSZ, acc, As, Bs);

  const int tx = threadIdx.x & 15, ty = threadIdx.x >> 4;
  const int h = n0 >> 6;
#pragma unroll
  for (int i = 0; i < 4; ++i) {
    const int s = m0 + ty * 4 + i;
    const int rel = (SEQ - 1) - s;
    const float4 o = make_float4(acc[i][0], acc[i][1], acc[i][2], acc[i][3]);
    *reinterpret_cast<float4*>(&rrb[((size_t)h * SEQ + rel) * HEAD_DIM + tx * 4]) = o;
  }
}

// ---------------------------------------------------------------------------
// Kernel 3: flash-style causal attention with relative-position term.
//   scores[t,s] = ((q_t+u)·k_s + (q_t+v)·rr[t-s]) * Dh^-0.5   (s <= t)
// Block: 64 q-rows, iterate 64-wide s-tiles. 256 threads, 4x4 microtile.
// ---------------------------------------------------------------------------
__global__ __launch_bounds__(256) void k_attn(const float* __restrict__ qb,
                                              const float* __restrict__ kb,
                                              const float* __restrict__ vb,
                                              const float* __restrict__ rrb,
                                              const float* __restrict__ uu,
                                              const float* __restrict__ vv,
                                              const unsigned char* __restrict__ kmask,
                                              float* __restrict__ ao) {
  __shared__ __align__(16) float Qus[64][68];
  __shared__ __align__(16) float Qvs[64][68];
  __shared__ __align__(16) float Ks[64][68];
  __shared__ __align__(16) float Vs[64][68];
  __shared__ __align__(16) float RRs[128][68];
  __shared__ __align__(16) float Ps[64][68];
  __shared__ float KMs[64];

  const int tid = threadIdx.x;
  const int tx = tid & 15, ty = tid >> 4;
  const int qt = blockIdx.x;
  const int bh = blockIdx.y;
  const int b = bh >> 4, h = bh & 15;
  const int t0 = qt * 64;

  const float* qbase = qb + ((size_t)bh * SEQ + t0) * HEAD_DIM;
  const float* kbase = kb + (size_t)bh * SEQ * HEAD_DIM;
  const float* vbase = vb + (size_t)bh * SEQ * HEAD_DIM;
  const float* rbase = rrb + (size_t)h * SEQ * HEAD_DIM;

  // Load Q tile, pre-adding u and v.
  for (int i = tid; i < 64 * 16; i += 256) {
    const int r = i >> 4;
    const int d4 = (i & 15) * 4;
    const float4 q4 = *reinterpret_cast<const float4*>(&qbase[r * HEAD_DIM + d4]);
    const float4 u4 = *reinterpret_cast<const float4*>(&uu[h * HEAD_DIM + d4]);
    const float4 v4 = *reinterpret_cast<const float4*>(&vv[h * HEAD_DIM + d4]);
    *reinterpret_cast<float4*>(&Qus[r][d4]) =
        make_float4(q4.x + u4.x, q4.y + u4.y, q4.z + u4.z, q4.w + u4.w);
    *reinterpret_cast<float4*>(&Qvs[r][d4]) =
        make_float4(q4.x + v4.x, q4.y + v4.y, q4.z + v4.z, q4.w + v4.w);
  }

  float m_r[4], l_r[4], acc[4][4] = {};
#pragma unroll
  for (int i = 0; i < 4; ++i) { m_r[i] = -1e30f; l_r[i] = 0.0f; }
  const float scale = 0.125f;  // 64^-0.5
  const int r0 = ty * 4, c0 = tx * 4;

  for (int st = 0; st <= qt; ++st) {
    const int s0 = st * 64;
    __syncthreads();  // prev PV done before overwriting K/V/RR/P
    for (int i = tid; i < 64 * 16; i += 256) {
      const int rr_ = i >> 4, d4 = (i & 15) * 4;
      *reinterpret_cast<float4*>(&Ks[rr_][d4]) =
          *reinterpret_cast<const float4*>(&kbase[(size_t)(s0 + rr_) * HEAD_DIM + d4]);
      *reinterpret_cast<float4*>(&Vs[rr_][d4]) =
          *reinterpret_cast<const float4*>(&vbase[(size_t)(s0 + rr_) * HEAD_DIM + d4]);
    }
    const int rel0 = t0 - s0 - 63;  // RRs[j] = rr[rel0 + j], j in [0,128)
    for (int i = tid; i < 128 * 16; i += 256) {
      const int j = i >> 4, d4 = (i & 15) * 4;
      const int rel = rel0 + j;
      float4 val = make_float4(0.f, 0.f, 0.f, 0.f);
      if (rel >= 0 && rel < SEQ)
        val = *reinterpret_cast<const float4*>(&rbase[(size_t)rel * HEAD_DIM + d4]);
      *reinterpret_cast<float4*>(&RRs[j][d4]) = val;
    }
    if (tid < 64)
      KMs[tid] = kmask[b * SEQ + s0 + tid] ? -1e30f : 0.0f;
    __syncthreads();

    // ---- scores: 4x4 per thread; rr row = (r - c) + 63 spans 7 diagonals ----
    float scr[4][4] = {};
    const int rbidx = r0 - c0 + 63;
#pragma unroll
    for (int d4 = 0; d4 < HEAD_DIM; d4 += 4) {
      float4 quv[4], qvv[4], kv4[4], rr7[7];
#pragma unroll
      for (int i = 0; i < 4; ++i) {
        quv[i] = *reinterpret_cast<const float4*>(&Qus[r0 + i][d4]);
        qvv[i] = *reinterpret_cast<const float4*>(&Qvs[r0 + i][d4]);
        kv4[i] = *reinterpret_cast<const float4*>(&Ks[c0 + i][d4]);
      }
#pragma unroll
      for (int dd = 0; dd < 7; ++dd)
        rr7[dd] = *reinterpret_cast<const float4*>(&RRs[rbidx + dd - 3][d4]);
#pragma unroll
      for (int i = 0; i < 4; ++i)
#pragma unroll
        for (int j = 0; j < 4; ++j) {
          const float4 rv = rr7[i - j + 3];
          float t = scr[i][j];
          t = fmaf(quv[i].x, kv4[j].x, t);
          t = fmaf(quv[i].y, kv4[j].y, t);
          t = fmaf(quv[i].z, kv4[j].z, t);
          t = fmaf(quv[i].w, kv4[j].w, t);
          t = fmaf(qvv[i].x, rv.x, t);
          t = fmaf(qvv[i].y, rv.y, t);
          t = fmaf(qvv[i].z, rv.z, t);
          t = fmaf(qvv[i].w, rv.w, t);
          scr[i][j] = t;
        }
    }

    // ---- mask + online softmax ----
    float rmax[4];
#pragma unroll
    for (int i = 0; i < 4; ++i) {
      rmax[i] = -1e30f;
      const int t = t0 + r0 + i;
#pragma unroll
      for (int j = 0; j < 4; ++j) {
        const int s = s0 + c0 + j;
        float val = scr[i][j] * scale + KMs[c0 + j];
        val = (s <= t) ? val : -1e30f;
        scr[i][j] = val;
        rmax[i] = fmaxf(rmax[i], val);
      }
    }
#pragma unroll
    for (int i = 0; i < 4; ++i)
#pragma unroll
      for (int mk = 1; mk <= 8; mk <<= 1)
        rmax[i] = fmaxf(rmax[i], __shfl_xor(rmax[i], mk, 16));

    float rsum[4];
#pragma unroll
    for (int i = 0; i < 4; ++i) {
      const float mnew = fmaxf(m_r[i], rmax[i]);
      const float corr = __expf(m_r[i] - mnew);
      m_r[i] = mnew;
      float sl = 0.f;
#pragma unroll
      for (int j = 0; j < 4; ++j) {
        const float p = __expf(scr[i][j] - mnew);
        scr[i][j] = p;
        sl += p;
      }
      rsum[i] = sl;
      l_r[i] *= corr;
#pragma unroll
      for (int j = 0; j < 4; ++j) acc[i][j] *= corr;
      *reinterpret_cast<float4*>(&Ps[r0 + i][c0]) =
          make_float4(scr[i][0], scr[i][1], scr[i][2], scr[i][3]);
    }
#pragma unroll
    for (int i = 0; i < 4; ++i) {
#pragma unroll
      for (int mk = 1; mk <= 8; mk <<= 1)
        rsum[i] += __shfl_xor(rsum[i], mk, 16);
      l_r[i] += rsum[i];
    }
    __syncthreads();  // Ps written by all before PV

    // ---- PV: acc[i][j] += P[r,s] * V[s, c0+j] ----
#pragma unroll 8
    for (int s = 0; s < 64; ++s) {
      const float4 v4 = *reinterpret_cast<const float4*>(&Vs[s][c0]);
#pragma unroll
      for (int i = 0; i < 4; ++i) {
        const float p = Ps[r0 + i][s];
        acc[i][0] = fmaf(p, v4.x, acc[i][0]);
        acc[i][1] = fmaf(p, v4.y, acc[i][1]);
        acc[i][2] = fmaf(p, v4.z, acc[i][2]);
        acc[i][3] = fmaf(p, v4.w, acc[i][3]);
      }
    }
  }

  // ---- epilogue: normalize, write [B,T,DIM] with heads interleaved ----
#pragma unroll
  for (int i = 0; i < 4; ++i) {
    const float inv = 1.0f / l_r[i];
    const int t = t0 + r0 + i;
    const float4 o = make_float4(acc[i][0] * inv, acc[i][1] * inv,
                                 acc[i][2] * inv, acc[i][3] * inv);
    *reinterpret_cast<float4*>(&ao[((size_t)b * SEQ + t) * DIMSZ + h * HEAD_DIM + c0]) = o;
  }
}

// ---------------------------------------------------------------------------
// Kernel 4: out = attn_out @ Wout + bout
// ---------------------------------------------------------------------------
__global__ __launch_bounds__(256) void k_gemm_out(const float* __restrict__ AO,
                                                  const float* __restrict__ Wout,
                                                  const float* __restrict__ bout,
                                                  float* __restrict__ out) {
  __shared__ __align__(16) float As[16][68];
  __shared__ __align__(16) float Bs[16][68];
  float acc[4][4] = {};
  const int n0 = blockIdx.x * 64;   // N = 1024
  const int m0 = blockIdx.y * 64;   // M = 4096
  gemm_mainloop(AO, DIMSZ, Wout, DIMSZ, m0, n0, DIMSZ, acc, As, Bs);

  const int tx = threadIdx.x & 15, ty = threadIdx.x >> 4;
  const float4 bias = *reinterpret_cast<const float4*>(&bout[n0 + tx * 4]);
#pragma unroll
  for (int i = 0; i < 4; ++i) {
    const int m = m0 + ty * 4 + i;
    const float4 o = make_float4(acc[i][0] + bias.x, acc[i][1] + bias.y,
                                 acc[i][2] + bias.z, acc[i][3] + bias.w);
    *reinterpret_cast<float4*>(&out[(size_t)m * DIMSZ + n0 + tx * 4]) = o;
  }
}

// ---------------------------------------------------------------------------
extern "C" void kernel_launch(void* const* d_in, const int* in_sizes, int n_in,
                              void* d_out, int out_size, void* d_ws, size_t ws_size,
                              hipStream_t stream) {
  const float* x     = (const float*)d_in[0];
  const float* r     = (const float*)d_in[1];
  const unsigned char* km = (const unsigned char*)d_in[2];
  const float* Wqkv  = (const float*)d_in[3];
  const float* Wr    = (const float*)d_in[4];
  const float* u     = (const float*)d_in[5];
  const float* v     = (const float*)d_in[6];
  const float* Wout  = (const float*)d_in[7];
  const float* bout  = (const float*)d_in[8];
  float* out = (float*)d_out;

  // workspace layout (floats)
  float* ws = (float*)d_ws;
  const size_t per_qkv = (size_t)BATCH * HEADS * SEQ * HEAD_DIM;  // 4,194,304
  float* qb  = ws;
  float* kb  = qb + per_qkv;
  float* vb  = kb + per_qkv;
  float* rrb = vb + per_qkv;                                       // H*T*Dh
  float* ao  = rrb + (size_t)HEADS * SEQ * HEAD_DIM;               // B*T*DIM

  k_gemm_qkv<<<dim3(48, 64), 256, 0, stream>>>(x, Wqkv, qb, kb, vb);
  k_gemm_r<<<dim3(16, 32), 256, 0, stream>>>(r, Wr, rrb);
  k_attn<<<dim3(32, 32), 256, 0, stream>>>(qb, kb, vb, rrb, u, v, km, ao);
  k_gemm_out<<<dim3(16, 64), 256, 0, stream>>>(ao, Wout, bout, out);
}

// Round 3
// 884.681 us; speedup vs baseline: 2.4676x; 2.4676x over previous
//
#include <hip/hip_runtime.h>
#include <hip/hip_bf16.h>

#define DIMSZ 1024
#define HEADS 16
#define HEAD_DIM 64
#define BATCH 2
#define SEQ 2048

typedef __attribute__((ext_vector_type(4))) short short4v;
typedef __attribute__((ext_vector_type(8))) short short8v;
typedef __attribute__((ext_vector_type(4))) float f32x4;

__device__ __forceinline__ unsigned short f2bf(float f) {
  unsigned int u = __float_as_uint(f);
  u += 0x7fffu + ((u >> 16) & 1u);
  return (unsigned short)(u >> 16);
}

// A/B-operand fragment load with sigma mapping: element e (lane-group g) holds
// k = k0 + 4g + (e&3) + 16*(e>>2). Rows padded to 68 bf16 (136B stride).
__device__ __forceinline__ short8v ldfrag(const unsigned short* base, int row, int k0, int g) {
  const short4v lo = *reinterpret_cast<const short4v*>(base + row * 68 + k0 + 4 * g);
  const short4v hi = *reinterpret_cast<const short4v*>(base + row * 68 + k0 + 16 + 4 * g);
  return __builtin_shufflevector(lo, hi, 0, 1, 2, 3, 4, 5, 6, 7);
}

// ---------------------------------------------------------------------------
// Shared fp32 GEMM mainloop (proven round 1): C_tile(64x64) = A @ B
// ---------------------------------------------------------------------------
__device__ __forceinline__ void gemm_mainloop(const float* __restrict__ A, int lda,
                                              const float* __restrict__ Bm, int ldb,
                                              int m0, int n0, int K,
                                              float acc[4][4],
                                              float (*As)[68], float (*Bs)[68]) {
  const int tid = threadIdx.x;
  const int tx = tid & 15, ty = tid >> 4;
  const int am = tid >> 2;
  const int ak = (tid & 3) * 4;
  const int bk = tid >> 4;
  const int bn = (tid & 15) * 4;

  for (int k0 = 0; k0 < K; k0 += 16) {
    const float4 a4 = *reinterpret_cast<const float4*>(&A[(size_t)(m0 + am) * lda + k0 + ak]);
    const float4 b4 = *reinterpret_cast<const float4*>(&Bm[(size_t)(k0 + bk) * ldb + n0 + bn]);
    __syncthreads();
    As[ak + 0][am] = a4.x;
    As[ak + 1][am] = a4.y;
    As[ak + 2][am] = a4.z;
    As[ak + 3][am] = a4.w;
    *reinterpret_cast<float4*>(&Bs[bk][bn]) = b4;
    __syncthreads();
#pragma unroll
    for (int kk = 0; kk < 16; ++kk) {
      const float4 av = *reinterpret_cast<const float4*>(&As[kk][ty * 4]);
      const float4 bv = *reinterpret_cast<const float4*>(&Bs[kk][tx * 4]);
      const float a[4] = {av.x, av.y, av.z, av.w};
      const float b[4] = {bv.x, bv.y, bv.z, bv.w};
#pragma unroll
      for (int i = 0; i < 4; ++i)
#pragma unroll
        for (int j = 0; j < 4; ++j)
          acc[i][j] = fmaf(a[i], b[j], acc[i][j]);
    }
  }
}

__global__ __launch_bounds__(256) void k_gemm_qkv(const float* __restrict__ X,
                                                  const float* __restrict__ W,
                                                  float* __restrict__ qb,
                                                  float* __restrict__ kb,
                                                  float* __restrict__ vb) {
  __shared__ __align__(16) float As[16][68];
  __shared__ __align__(16) float Bs[16][68];
  float acc[4][4] = {};
  const int n0 = blockIdx.x * 64;
  const int m0 = blockIdx.y * 64;
  gemm_mainloop(X, DIMSZ, W, 3 * DIMSZ, m0, n0, DIMSZ, acc, As, Bs);

  const int tx = threadIdx.x & 15, ty = threadIdx.x >> 4;
  const int comp = n0 >> 10;
  const int h = (n0 >> 6) & 15;
  const int b = m0 >> 11;
  float* dst = (comp == 0) ? qb : (comp == 1 ? kb : vb);
#pragma unroll
  for (int i = 0; i < 4; ++i) {
    const int t = (m0 & (SEQ - 1)) + ty * 4 + i;
    const float4 o = make_float4(acc[i][0], acc[i][1], acc[i][2], acc[i][3]);
    *reinterpret_cast<float4*>(&dst[(((size_t)(b * HEADS + h)) * SEQ + t) * HEAD_DIM + tx * 4]) = o;
  }
}

__global__ __launch_bounds__(256) void k_gemm_r(const float* __restrict__ R,
                                                const float* __restrict__ Wr,
                                                float* __restrict__ rrb) {
  __shared__ __align__(16) float As[16][68];
  __shared__ __align__(16) float Bs[16][68];
  float acc[4][4] = {};
  const int n0 = blockIdx.x * 64;
  const int m0 = blockIdx.y * 64;
  gemm_mainloop(R, DIMSZ, Wr, DIMSZ, m0, n0, DIMSZ, acc, As, Bs);

  const int tx = threadIdx.x & 15, ty = threadIdx.x >> 4;
  const int h = n0 >> 6;
#pragma unroll
  for (int i = 0; i < 4; ++i) {
    const int s = m0 + ty * 4 + i;
    const int rel = (SEQ - 1) - s;
    const float4 o = make_float4(acc[i][0], acc[i][1], acc[i][2], acc[i][3]);
    *reinterpret_cast<float4*>(&rrb[((size_t)h * SEQ + rel) * HEAD_DIM + tx * 4]) = o;
  }
}

// ---------------------------------------------------------------------------
// MFMA flash attention (bf16 inputs, fp32 softmax/accum), swapped operands.
//   S^T = mfma(K, Qu)   -> D[s][q]
//   G^T = mfma(RR, Qv)  -> D[j][q], diagonal-gathered BD = G[q - s + 63]
//   O^T = mfma(V^T, P)  -> D[dv][q], P fed in-register from softmax
// ---------------------------------------------------------------------------
__global__ __launch_bounds__(256) void k_attn_mfma(const float* __restrict__ qb,
                                                   const float* __restrict__ kb,
                                                   const float* __restrict__ vb,
                                                   const float* __restrict__ rrb,
                                                   const float* __restrict__ uu,
                                                   const float* __restrict__ vv,
                                                   const unsigned char* __restrict__ kmask,
                                                   float* __restrict__ ao) {
  __shared__ __align__(16) unsigned short Kl[64 * 68];
  __shared__ __align__(16) unsigned short Vt[64 * 68];
  __shared__ __align__(16) unsigned short RRl[128 * 68];
  __shared__ float KMl[64];
  __shared__ __align__(16) float Gw_all[4][1440];  // wave-private scratch

  const int tid = threadIdx.x;
  const int wid = tid >> 6;       // wave id = q-block
  const int lane = tid & 63;
  const int g = lane >> 4;        // k-group
  const int r16 = lane & 15;      // row (A) / col q (B, C/D)
  const int qt = blockIdx.x, bh = blockIdx.y;
  const int b = bh >> 4, h = bh & 15;
  const int t0 = qt * 64;
  float* Gw = Gw_all[wid];

  const float* qbase = qb + (size_t)bh * SEQ * HEAD_DIM;
  const float* kbase = kb + (size_t)bh * SEQ * HEAD_DIM;
  const float* vbase = vb + (size_t)bh * SEQ * HEAD_DIM;
  const float* rbase = rrb + (size_t)h * SEQ * HEAD_DIM;

  // ---- hoist Q fragments (B-operand, sigma mapping), pre-adding u and v ----
  short8v qu[2], qv[2];
  {
    const float* qrow = qbase + (size_t)(t0 + wid * 16 + r16) * HEAD_DIM;
#pragma unroll
    for (int ks = 0; ks < 2; ++ks) {
      const int d0 = 32 * ks + 4 * g;
      const float4 ql = *reinterpret_cast<const float4*>(qrow + d0);
      const float4 qh = *reinterpret_cast<const float4*>(qrow + d0 + 16);
      const float4 ul = *reinterpret_cast<const float4*>(uu + h * HEAD_DIM + d0);
      const float4 uh = *reinterpret_cast<const float4*>(uu + h * HEAD_DIM + d0 + 16);
      const float4 wl = *reinterpret_cast<const float4*>(vv + h * HEAD_DIM + d0);
      const float4 wh = *reinterpret_cast<const float4*>(vv + h * HEAD_DIM + d0 + 16);
      short8v a, c;
      a[0] = (short)f2bf(ql.x + ul.x); a[1] = (short)f2bf(ql.y + ul.y);
      a[2] = (short)f2bf(ql.z + ul.z); a[3] = (short)f2bf(ql.w + ul.w);
      a[4] = (short)f2bf(qh.x + uh.x); a[5] = (short)f2bf(qh.y + uh.y);
      a[6] = (short)f2bf(qh.z + uh.z); a[7] = (short)f2bf(qh.w + uh.w);
      c[0] = (short)f2bf(ql.x + wl.x); c[1] = (short)f2bf(ql.y + wl.y);
      c[2] = (short)f2bf(ql.z + wl.z); c[3] = (short)f2bf(ql.w + wl.w);
      c[4] = (short)f2bf(qh.x + wh.x); c[5] = (short)f2bf(qh.y + wh.y);
      c[6] = (short)f2bf(qh.z + wh.z); c[7] = (short)f2bf(qh.w + wh.w);
      qu[ks] = a; qv[ks] = c;
    }
  }

  f32x4 oacc[4];
#pragma unroll
  for (int df = 0; df < 4; ++df) oacc[df] = (f32x4){0.f, 0.f, 0.f, 0.f};
  float m_r = -1e30f, l_r = 0.f;

  for (int st = 0; st <= qt; ++st) {
    const int s0 = st * 64;
    const int rel0 = t0 - s0 - 63;  // RRl row j <-> rel = rel0 + j

    __syncthreads();  // all waves done reading K/Vt/RR of previous tile

    // ---- stage K (natural), V (transposed), RR window, key-mask ----
    {
      const int srow = tid >> 2;
      const int cq = (tid & 3) << 4;
      const float* kr = kbase + (size_t)(s0 + srow) * HEAD_DIM + cq;
      const float* vr = vbase + (size_t)(s0 + srow) * HEAD_DIM + cq;
#pragma unroll
      for (int i = 0; i < 4; ++i) {
        const float4 kv = *reinterpret_cast<const float4*>(kr + 4 * i);
        short4v p;
        p[0] = (short)f2bf(kv.x); p[1] = (short)f2bf(kv.y);
        p[2] = (short)f2bf(kv.z); p[3] = (short)f2bf(kv.w);
        *reinterpret_cast<short4v*>(&Kl[srow * 68 + cq + 4 * i]) = p;
        const float4 vv4 = *reinterpret_cast<const float4*>(vr + 4 * i);
        Vt[(cq + 4 * i + 0) * 68 + srow] = f2bf(vv4.x);
        Vt[(cq + 4 * i + 1) * 68 + srow] = f2bf(vv4.y);
        Vt[(cq + 4 * i + 2) * 68 + srow] = f2bf(vv4.z);
        Vt[(cq + 4 * i + 3) * 68 + srow] = f2bf(vv4.w);
      }
      const int jr = tid >> 1;
      const int ch = (tid & 1) << 5;
      const int rel = rel0 + jr;
      const bool ok = (rel >= 0) && (rel < SEQ);
      const float* rr = ok ? (rbase + (size_t)rel * HEAD_DIM + ch) : nullptr;
#pragma unroll
      for (int i = 0; i < 8; ++i) {
        float4 rv = make_float4(0.f, 0.f, 0.f, 0.f);
        if (ok) rv = *reinterpret_cast<const float4*>(rr + 4 * i);
        short4v p;
        p[0] = (short)f2bf(rv.x); p[1] = (short)f2bf(rv.y);
        p[2] = (short)f2bf(rv.z); p[3] = (short)f2bf(rv.w);
        *reinterpret_cast<short4v*>(&RRl[jr * 68 + ch + 4 * i]) = p;
      }
      if (tid < 64) KMl[tid] = kmask[(size_t)b * SEQ + s0 + tid] ? -1e30f : 0.f;
    }
    __syncthreads();

    // ---- S^T = K . Qu  (AC term) ----
    f32x4 sacc[4];
#pragma unroll
    for (int sf = 0; sf < 4; ++sf) sacc[sf] = (f32x4){0.f, 0.f, 0.f, 0.f};
#pragma unroll
    for (int sf = 0; sf < 4; ++sf)
#pragma unroll
      for (int ks = 0; ks < 2; ++ks)
        sacc[sf] = __builtin_amdgcn_mfma_f32_16x16x32_bf16(
            ldfrag(Kl, 16 * sf + r16, 32 * ks, g), qu[ks], sacc[sf], 0, 0, 0);

    // ---- G^T = RR . Qv, only this wave's 5-fragment j-window ----
#pragma unroll
    for (int fj = 0; fj < 5; ++fj) {
      f32x4 gacc = (f32x4){0.f, 0.f, 0.f, 0.f};
#pragma unroll
      for (int ks = 0; ks < 2; ++ks)
        gacc = __builtin_amdgcn_mfma_f32_16x16x32_bf16(
            ldfrag(RRl, 16 * (wid + fj) + r16, 32 * ks, g), qv[ks], gacc, 0, 0, 0);
#pragma unroll
      for (int r = 0; r < 4; ++r)
        Gw[(16 * fj + 4 * g + r) * 18 + r16] = gacc[r];
    }
    asm volatile("s_waitcnt lgkmcnt(0)" ::: "memory");  // wave-private RAW
    __builtin_amdgcn_sched_barrier(0);                  // rule #18 fence

    // ---- diagonal gather + mask + online softmax ----
    float scr[4][4];
    float rmax = -1e30f;
    const int tl = wid * 16 + r16;  // t - t0 for this lane's q
    const bool diag = (st == qt);
#pragma unroll
    for (int sf = 0; sf < 4; ++sf) {
#pragma unroll
      for (int r = 0; r < 4; ++r) {
        const int sp = 16 * sf + 4 * g + r;
        const float bd = Gw[(63 + r16 - sp) * 18 + r16];
        float sc = (sacc[sf][r] + bd) * 0.125f + KMl[sp];
        if (diag && sp > tl) sc = -1e30f;
        scr[sf][r] = sc;
        rmax = fmaxf(rmax, sc);
      }
    }
    rmax = fmaxf(rmax, __shfl_xor(rmax, 16, 64));
    rmax = fmaxf(rmax, __shfl_xor(rmax, 32, 64));
    const float mnew = fmaxf(m_r, rmax);
    const float corr = __expf(m_r - mnew);
    m_r = mnew;
    float rsum = 0.f;
#pragma unroll
    for (int sf = 0; sf < 4; ++sf)
#pragma unroll
      for (int r = 0; r < 4; ++r) {
        const float p = __expf(scr[sf][r] - mnew);
        scr[sf][r] = p;
        rsum += p;
      }
    rsum += __shfl_xor(rsum, 16, 64);
    rsum += __shfl_xor(rsum, 32, 64);
    l_r = l_r * corr + rsum;
#pragma unroll
    for (int df = 0; df < 4; ++df)
#pragma unroll
      for (int r = 0; r < 4; ++r) oacc[df][r] *= corr;

    // ---- PV: O^T += V^T . P, P packed in-register with matching sigma ----
#pragma unroll
    for (int c = 0; c < 2; ++c) {
      short8v pb;
#pragma unroll
      for (int e = 0; e < 4; ++e) {
        pb[e] = (short)f2bf(scr[2 * c][e]);
        pb[e + 4] = (short)f2bf(scr[2 * c + 1][e]);
      }
#pragma unroll
      for (int df = 0; df < 4; ++df)
        oacc[df] = __builtin_amdgcn_mfma_f32_16x16x32_bf16(
            ldfrag(Vt, 16 * df + r16, 32 * c, g), pb, oacc[df], 0, 0, 0);
    }
  }

  // ---- epilogue: normalize, transpose via wave-private LDS, coalesced store ----
  const float inv = (l_r > 0.f) ? (1.0f / l_r) : 0.f;
#pragma unroll
  for (int df = 0; df < 4; ++df)
#pragma unroll
    for (int r = 0; r < 4; ++r)
      Gw[r16 * 68 + 16 * df + 4 * g + r] = oacc[df][r] * inv;
  asm volatile("s_waitcnt lgkmcnt(0)" ::: "memory");
  __builtin_amdgcn_sched_barrier(0);
  const int orow = lane >> 2;
  const int ocol = (lane & 3) * 16;
  float* aorow = ao + ((size_t)b * SEQ + t0 + wid * 16 + orow) * DIMSZ + h * HEAD_DIM + ocol;
#pragma unroll
  for (int i = 0; i < 4; ++i)
    *reinterpret_cast<float4*>(aorow + 4 * i) =
        *reinterpret_cast<const float4*>(&Gw[orow * 68 + ocol + 4 * i]);
}

// ---------------------------------------------------------------------------
__global__ __launch_bounds__(256) void k_gemm_out(const float* __restrict__ AO,
                                                  const float* __restrict__ Wout,
                                                  const float* __restrict__ bout,
                                                  float* __restrict__ out) {
  __shared__ __align__(16) float As[16][68];
  __shared__ __align__(16) float Bs[16][68];
  float acc[4][4] = {};
  const int n0 = blockIdx.x * 64;
  const int m0 = blockIdx.y * 64;
  gemm_mainloop(AO, DIMSZ, Wout, DIMSZ, m0, n0, DIMSZ, acc, As, Bs);

  const int tx = threadIdx.x & 15, ty = threadIdx.x >> 4;
  const float4 bias = *reinterpret_cast<const float4*>(&bout[n0 + tx * 4]);
#pragma unroll
  for (int i = 0; i < 4; ++i) {
    const int m = m0 + ty * 4 + i;
    const float4 o = make_float4(acc[i][0] + bias.x, acc[i][1] + bias.y,
                                 acc[i][2] + bias.z, acc[i][3] + bias.w);
    *reinterpret_cast<float4*>(&out[(size_t)m * DIMSZ + n0 + tx * 4]) = o;
  }
}

// ---------------------------------------------------------------------------
extern "C" void kernel_launch(void* const* d_in, const int* in_sizes, int n_in,
                              void* d_out, int out_size, void* d_ws, size_t ws_size,
                              hipStream_t stream) {
  const float* x     = (const float*)d_in[0];
  const float* r     = (const float*)d_in[1];
  const unsigned char* km = (const unsigned char*)d_in[2];
  const float* Wqkv  = (const float*)d_in[3];
  const float* Wr    = (const float*)d_in[4];
  const float* u     = (const float*)d_in[5];
  const float* v     = (const float*)d_in[6];
  const float* Wout  = (const float*)d_in[7];
  const float* bout  = (const float*)d_in[8];
  float* out = (float*)d_out;

  float* ws = (float*)d_ws;
  const size_t per_qkv = (size_t)BATCH * HEADS * SEQ * HEAD_DIM;
  float* qb  = ws;
  float* kb  = qb + per_qkv;
  float* vb  = kb + per_qkv;
  float* rrb = vb + per_qkv;
  float* ao  = rrb + (size_t)HEADS * SEQ * HEAD_DIM;

  k_gemm_qkv<<<dim3(48, 64), 256, 0, stream>>>(x, Wqkv, qb, kb, vb);
  k_gemm_r<<<dim3(16, 32), 256, 0, stream>>>(r, Wr, rrb);
  k_attn_mfma<<<dim3(32, 32), 256, 0, stream>>>(qb, kb, vb, rrb, u, v, km, ao);
  k_gemm_out<<<dim3(16, 64), 256, 0, stream>>>(ao, Wout, bout, out);
}

// Round 6
// 475.389 us; speedup vs baseline: 4.5921x; 1.8610x over previous
//
#include <hip/hip_runtime.h>
#include <hip/hip_bf16.h>

#define DIMSZ 1024
#define HEADS 16
#define HEAD_DIM 64
#define BATCH 2
#define SEQ 2048
#define KDIM 1024

typedef __attribute__((ext_vector_type(4))) short short4v;
typedef __attribute__((ext_vector_type(8))) short short8v;
typedef __attribute__((ext_vector_type(4))) float f32x4;

__device__ __forceinline__ unsigned short f2bf(float f) {
  unsigned int u = __float_as_uint(f);
  u += 0x7fffu + ((u >> 16) & 1u);
  return (unsigned short)(u >> 16);
}
__device__ __forceinline__ float bf2f(unsigned short h) {
  return __uint_as_float(((unsigned int)h) << 16);
}
__device__ __forceinline__ void split2(float f, unsigned short& h, unsigned short& l) {
  h = f2bf(f);
  l = f2bf(f - bf2f(h));
}

// Fragment load with sigma mapping: element e (k-group g) holds
// k = k0 + 4g + (e&3) + 16*(e>>2). Same permutation for A, B and P operands,
// so the contraction is invariant to the HW k-mapping (proven round 3).
__device__ __forceinline__ short8v ldfragS(const unsigned short* base, int row, int stride,
                                           int k0, int g) {
  const short4v lo = *reinterpret_cast<const short4v*>(base + row * stride + k0 + 4 * g);
  const short4v hi = *reinterpret_cast<const short4v*>(base + row * stride + k0 + 16 + 4 * g);
  return __builtin_shufflevector(lo, hi, 0, 1, 2, 3, 4, 5, 6, 7);
}

// ---------------------------------------------------------------------------
// Conversion: fp32 -> (hi, lo) bf16 planes (same layout)
// ---------------------------------------------------------------------------
__global__ __launch_bounds__(256) void k_conv_split(const float* __restrict__ in,
                                                    unsigned short* __restrict__ hi,
                                                    unsigned short* __restrict__ lo,
                                                    int n4) {
  int idx = blockIdx.x * 256 + threadIdx.x;
  const int stride = gridDim.x * 256;
  for (; idx < n4; idx += stride) {
    const float4 f = reinterpret_cast<const float4*>(in)[idx];
    short4v h4, l4;
    unsigned short h, l;
    split2(f.x, h, l); h4[0] = (short)h; l4[0] = (short)l;
    split2(f.y, h, l); h4[1] = (short)h; l4[1] = (short)l;
    split2(f.z, h, l); h4[2] = (short)h; l4[2] = (short)l;
    split2(f.w, h, l); h4[3] = (short)h; l4[3] = (short)l;
    reinterpret_cast<short4v*>(hi)[idx] = h4;
    reinterpret_cast<short4v*>(lo)[idx] = l4;
  }
}

// ---------------------------------------------------------------------------
// Conversion: W [KDIM][N] fp32 -> transposed (hi, lo) planes [N][KDIM] bf16
// ---------------------------------------------------------------------------
__global__ __launch_bounds__(256) void k_conv_wT(const float* __restrict__ W,
                                                 unsigned short* __restrict__ th,
                                                 unsigned short* __restrict__ tl,
                                                 int N) {
  const int n = blockIdx.x * 256 + threadIdx.x;
  const int k0 = blockIdx.y * 16;
  unsigned short h16[16], l16[16];
#pragma unroll
  for (int i = 0; i < 16; ++i)
    split2(W[(size_t)(k0 + i) * N + n], h16[i], l16[i]);
  short8v o;
  unsigned short* dh = th + (size_t)n * KDIM + k0;
  unsigned short* dl = tl + (size_t)n * KDIM + k0;
#pragma unroll
  for (int i = 0; i < 8; ++i) o[i] = (short)h16[i];
  *reinterpret_cast<short8v*>(dh) = o;
#pragma unroll
  for (int i = 0; i < 8; ++i) o[i] = (short)h16[8 + i];
  *reinterpret_cast<short8v*>(dh + 8) = o;
#pragma unroll
  for (int i = 0; i < 8; ++i) o[i] = (short)l16[i];
  *reinterpret_cast<short8v*>(dl) = o;
#pragma unroll
  for (int i = 0; i < 8; ++i) o[i] = (short)l16[8 + i];
  *reinterpret_cast<short8v*>(dl + 8) = o;
}

// ---------------------------------------------------------------------------
// Split-bf16 MFMA GEMM core: 128x128 tile, BK=32, 4 waves (2x2), 64x64/wave.
// A planes [M][KDIM], B planes [N][KDIM] (pre-transposed weights).
// 3-term: Ah*Bh + Ah*Bl + Al*Bh, fp32 accumulate -> ~fp32-class precision.
// LDS: 4 planes of [128][40] shorts.
// FIX vs round 4: each thread stages 16 shorts per plane (was 8 -> half of
// every LDS row uninitialized -> NaN). Tile = 128x32 = 4096 shorts/plane;
// 256 threads x 16 = 4096. Coverage now exact.
// ---------------------------------------------------------------------------
__device__ __forceinline__ void split_gemm_core(const unsigned short* __restrict__ Ah,
                                                const unsigned short* __restrict__ Al,
                                                const unsigned short* __restrict__ Bh,
                                                const unsigned short* __restrict__ Bl,
                                                int m0, int n0, unsigned short* sm,
                                                f32x4 acc[4][4]) {
  unsigned short* sAh = sm;
  unsigned short* sAl = sm + 5120;
  unsigned short* sBh = sm + 10240;
  unsigned short* sBl = sm + 15360;
  const int tid = threadIdx.x;
  const int lane = tid & 63, wid = tid >> 6;
  const int g = lane >> 4, r16 = lane & 15;
  const int wm = wid >> 1, wn = wid & 1;
  const int srow = tid >> 1, sh16 = (tid & 1) * 16;
  const size_t aoff = (size_t)(m0 + srow) * KDIM + sh16;
  const size_t boff = (size_t)(n0 + srow) * KDIM + sh16;
  const int sws = srow * 40 + sh16;

  short8v ah0 = *reinterpret_cast<const short8v*>(Ah + aoff);
  short8v ah1 = *reinterpret_cast<const short8v*>(Ah + aoff + 8);
  short8v al0 = *reinterpret_cast<const short8v*>(Al + aoff);
  short8v al1 = *reinterpret_cast<const short8v*>(Al + aoff + 8);
  short8v bh0 = *reinterpret_cast<const short8v*>(Bh + boff);
  short8v bh1 = *reinterpret_cast<const short8v*>(Bh + boff + 8);
  short8v bl0 = *reinterpret_cast<const short8v*>(Bl + boff);
  short8v bl1 = *reinterpret_cast<const short8v*>(Bl + boff + 8);

  for (int k0 = 0; k0 < KDIM; k0 += 32) {
    __syncthreads();
    *reinterpret_cast<short8v*>(sAh + sws) = ah0;
    *reinterpret_cast<short8v*>(sAh + sws + 8) = ah1;
    *reinterpret_cast<short8v*>(sAl + sws) = al0;
    *reinterpret_cast<short8v*>(sAl + sws + 8) = al1;
    *reinterpret_cast<short8v*>(sBh + sws) = bh0;
    *reinterpret_cast<short8v*>(sBh + sws + 8) = bh1;
    *reinterpret_cast<short8v*>(sBl + sws) = bl0;
    *reinterpret_cast<short8v*>(sBl + sws + 8) = bl1;
    __syncthreads();
    if (k0 + 32 < KDIM) {  // prefetch next tile under this tile's MFMA
      ah0 = *reinterpret_cast<const short8v*>(Ah + aoff + k0 + 32);
      ah1 = *reinterpret_cast<const short8v*>(Ah + aoff + k0 + 40);
      al0 = *reinterpret_cast<const short8v*>(Al + aoff + k0 + 32);
      al1 = *reinterpret_cast<const short8v*>(Al + aoff + k0 + 40);
      bh0 = *reinterpret_cast<const short8v*>(Bh + boff + k0 + 32);
      bh1 = *reinterpret_cast<const short8v*>(Bh + boff + k0 + 40);
      bl0 = *reinterpret_cast<const short8v*>(Bl + boff + k0 + 32);
      bl1 = *reinterpret_cast<const short8v*>(Bl + boff + k0 + 40);
    }
    short8v fah[4], fal[4], fbh[4], fbl[4];
#pragma unroll
    for (int i = 0; i < 4; ++i) {
      fah[i] = ldfragS(sAh, wm * 64 + i * 16 + r16, 40, 0, g);
      fal[i] = ldfragS(sAl, wm * 64 + i * 16 + r16, 40, 0, g);
      fbh[i] = ldfragS(sBh, wn * 64 + i * 16 + r16, 40, 0, g);
      fbl[i] = ldfragS(sBl, wn * 64 + i * 16 + r16, 40, 0, g);
    }
#pragma unroll
    for (int mf = 0; mf < 4; ++mf)
#pragma unroll
      for (int nf = 0; nf < 4; ++nf) {
        acc[mf][nf] = __builtin_amdgcn_mfma_f32_16x16x32_bf16(fah[mf], fbh[nf], acc[mf][nf], 0, 0, 0);
        acc[mf][nf] = __builtin_amdgcn_mfma_f32_16x16x32_bf16(fah[mf], fbl[nf], acc[mf][nf], 0, 0, 0);
        acc[mf][nf] = __builtin_amdgcn_mfma_f32_16x16x32_bf16(fal[mf], fbh[nf], acc[mf][nf], 0, 0, 0);
      }
  }
  __syncthreads();  // LDS free for epilogue scratch reuse
}

#define GEMM_PROLOG                                        \
  __shared__ __align__(16) unsigned short sm[20480];       \
  f32x4 acc[4][4];                                         \
  _Pragma("unroll") for (int i = 0; i < 4; ++i)            \
      _Pragma("unroll") for (int j = 0; j < 4; ++j)        \
          acc[i][j] = (f32x4){0.f, 0.f, 0.f, 0.f};         \
  const int n0 = blockIdx.x * 128;                         \
  const int m0 = blockIdx.y * 128;                         \
  const int tid = threadIdx.x;                             \
  const int lane = tid & 63, wid = tid >> 6;               \
  const int g = lane >> 4, r16 = lane & 15;                \
  const int wm = wid >> 1, wn = wid & 1;

// ---------------------------------------------------------------------------
// qkv GEMM: A = x planes, B = Wqkv^T planes. Outputs:
//   q,k bf16 [bh][t][d] (coalesced via per-wave LDS fragment transpose),
//   v  bf16 [bh][d][t]  (direct transposed 8B stores from C-layout)
// ---------------------------------------------------------------------------
__global__ __launch_bounds__(256) void k_gemm_bf_qkv(
    const unsigned short* __restrict__ Xh, const unsigned short* __restrict__ Xl,
    const unsigned short* __restrict__ Wh, const unsigned short* __restrict__ Wl,
    unsigned short* __restrict__ qbf, unsigned short* __restrict__ kbf,
    unsigned short* __restrict__ vtb) {
  GEMM_PROLOG
  split_gemm_core(Xh, Xl, Wh, Wl, m0, n0, sm, acc);

  const int n_w = n0 + wn * 64;
  const int comp = n_w >> 10;
  const int h = (n_w >> 6) & 15;
  if (comp == 2) {
    // v: direct transposed stores (reg quad = 4 consecutive t at fixed d)
#pragma unroll
    for (int mf = 0; mf < 4; ++mf) {
      const int m = m0 + wm * 64 + mf * 16 + 4 * g;
      const int b = m >> 11, t = m & (SEQ - 1);
#pragma unroll
      for (int nf = 0; nf < 4; ++nf) {
        const int d = nf * 16 + r16;
        short4v p;
#pragma unroll
        for (int r = 0; r < 4; ++r) p[r] = (short)f2bf(acc[mf][nf][r]);
        *reinterpret_cast<short4v*>(
            vtb + ((size_t)(b * HEADS + h) * HEAD_DIM + d) * SEQ + t) = p;
      }
    }
  } else {
    unsigned short* dst = comp ? kbf : qbf;
    float* scr = reinterpret_cast<float*>(sm) + wid * 1088;  // per-wave 16x68
    const int rr_ = lane >> 2, cc = (lane & 3) * 16;
    for (int mf = 0; mf < 4; ++mf) {
#pragma unroll
      for (int nf = 0; nf < 4; ++nf)
#pragma unroll
        for (int r = 0; r < 4; ++r)
          scr[(4 * g + r) * 68 + nf * 16 + r16] = acc[mf][nf][r];
      asm volatile("s_waitcnt lgkmcnt(0)" ::: "memory");
      __builtin_amdgcn_sched_barrier(0);
      const int m = m0 + wm * 64 + mf * 16 + rr_;
      const int b = m >> 11, t = m & (SEQ - 1);
      unsigned short* drow = dst + ((size_t)(b * HEADS + h) * SEQ + t) * HEAD_DIM + cc;
      short8v o0, o1;
#pragma unroll
      for (int i = 0; i < 8; ++i) {
        o0[i] = (short)f2bf(scr[rr_ * 68 + cc + i]);
        o1[i] = (short)f2bf(scr[rr_ * 68 + cc + 8 + i]);
      }
      *reinterpret_cast<short8v*>(drow) = o0;
      *reinterpret_cast<short8v*>(drow + 8) = o1;
      asm volatile("s_waitcnt lgkmcnt(0)" ::: "memory");
      __builtin_amdgcn_sched_barrier(0);
    }
  }
}

// ---------------------------------------------------------------------------
// r GEMM: rr bf16 [h][rel][d], rel = 2047 - s (reversed)
// ---------------------------------------------------------------------------
__global__ __launch_bounds__(256) void k_gemm_bf_r(
    const unsigned short* __restrict__ Rh, const unsigned short* __restrict__ Rl,
    const unsigned short* __restrict__ Wh, const unsigned short* __restrict__ Wl,
    unsigned short* __restrict__ rrbf) {
  GEMM_PROLOG
  split_gemm_core(Rh, Rl, Wh, Wl, m0, n0, sm, acc);

  const int n_w = n0 + wn * 64;
  const int h = n_w >> 6;
  float* scr = reinterpret_cast<float*>(sm) + wid * 1088;
  const int rr_ = lane >> 2, cc = (lane & 3) * 16;
  for (int mf = 0; mf < 4; ++mf) {
#pragma unroll
    for (int nf = 0; nf < 4; ++nf)
#pragma unroll
      for (int r = 0; r < 4; ++r)
        scr[(4 * g + r) * 68 + nf * 16 + r16] = acc[mf][nf][r];
    asm volatile("s_waitcnt lgkmcnt(0)" ::: "memory");
    __builtin_amdgcn_sched_barrier(0);
    const int s = m0 + wm * 64 + mf * 16 + rr_;
    const int rel = (SEQ - 1) - s;
    unsigned short* drow = rrbf + ((size_t)h * SEQ + rel) * HEAD_DIM + cc;
    short8v o0, o1;
#pragma unroll
    for (int i = 0; i < 8; ++i) {
      o0[i] = (short)f2bf(scr[rr_ * 68 + cc + i]);
      o1[i] = (short)f2bf(scr[rr_ * 68 + cc + 8 + i]);
    }
    *reinterpret_cast<short8v*>(drow) = o0;
    *reinterpret_cast<short8v*>(drow + 8) = o1;
    asm volatile("s_waitcnt lgkmcnt(0)" ::: "memory");
    __builtin_amdgcn_sched_barrier(0);
  }
}

// ---------------------------------------------------------------------------
// out GEMM: A = ao planes, B = Wout^T planes, + bias -> fp32 out
// ---------------------------------------------------------------------------
__global__ __launch_bounds__(256) void k_gemm_bf_out(
    const unsigned short* __restrict__ Ah, const unsigned short* __restrict__ Al,
    const unsigned short* __restrict__ Wh, const unsigned short* __restrict__ Wl,
    const float* __restrict__ bout, float* __restrict__ out) {
  GEMM_PROLOG
  split_gemm_core(Ah, Al, Wh, Wl, m0, n0, sm, acc);

  const int n_w = n0 + wn * 64;
  float* scr = reinterpret_cast<float*>(sm) + wid * 1088;
  const int rr_ = lane >> 2, cc = (lane & 3) * 16;
  for (int mf = 0; mf < 4; ++mf) {
#pragma unroll
    for (int nf = 0; nf < 4; ++nf)
#pragma unroll
      for (int r = 0; r < 4; ++r)
        scr[(4 * g + r) * 68 + nf * 16 + r16] = acc[mf][nf][r];
    asm volatile("s_waitcnt lgkmcnt(0)" ::: "memory");
    __builtin_amdgcn_sched_barrier(0);
    const int m = m0 + wm * 64 + mf * 16 + rr_;
    float* orow = out + (size_t)m * DIMSZ + n_w + cc;
#pragma unroll
    for (int c4 = 0; c4 < 4; ++c4) {
      const float4 bias = *reinterpret_cast<const float4*>(&bout[n_w + cc + 4 * c4]);
      float4 o;
      o.x = scr[rr_ * 68 + cc + 4 * c4 + 0] + bias.x;
      o.y = scr[rr_ * 68 + cc + 4 * c4 + 1] + bias.y;
      o.z = scr[rr_ * 68 + cc + 4 * c4 + 2] + bias.z;
      o.w = scr[rr_ * 68 + cc + 4 * c4 + 3] + bias.w;
      *reinterpret_cast<float4*>(orow + 4 * c4) = o;
    }
    asm volatile("s_waitcnt lgkmcnt(0)" ::: "memory");
    __builtin_amdgcn_sched_barrier(0);
  }
}

// ---------------------------------------------------------------------------
// MFMA flash attention, bf16 inputs (pre-converted), swapped operands.
//   S^T = mfma(K, Qu); G^T = mfma(RR, Qv) diag-gathered; O^T = mfma(V^T, P).
// Staging is pure b128 copies. Epilogue emits ao as (hi, lo) bf16 planes.
// ---------------------------------------------------------------------------
__global__ __launch_bounds__(256) void k_attn_mfma(const unsigned short* __restrict__ qbf,
                                                   const unsigned short* __restrict__ kbf,
                                                   const unsigned short* __restrict__ vtb,
                                                   const unsigned short* __restrict__ rrbf,
                                                   const float* __restrict__ uu,
                                                   const float* __restrict__ vv,
                                                   const unsigned char* __restrict__ kmask,
                                                   unsigned short* __restrict__ aoh,
                                                   unsigned short* __restrict__ aol) {
  __shared__ __align__(16) unsigned short Kl[64 * 72];
  __shared__ __align__(16) unsigned short Vt[64 * 72];
  __shared__ __align__(16) unsigned short RRl[128 * 72];
  __shared__ float KMl[64];
  __shared__ __align__(16) float Gw_all[4][1440];  // wave-private scratch

  const int tid = threadIdx.x;
  const int wid = tid >> 6;
  const int lane = tid & 63;
  const int g = lane >> 4;
  const int r16 = lane & 15;
  const int qt = blockIdx.x, bh = blockIdx.y;
  const int b = bh >> 4, h = bh & 15;
  const int t0 = qt * 64;
  float* Gw = Gw_all[wid];

  const unsigned short* kbase = kbf + (size_t)bh * SEQ * HEAD_DIM;
  const unsigned short* vbase = vtb + (size_t)bh * HEAD_DIM * SEQ;
  const unsigned short* rbase = rrbf + (size_t)h * SEQ * HEAD_DIM;

  // ---- hoist Q fragments, adding u and v in fp32 ----
  short8v qu[2], qv[2];
  {
    const unsigned short* qrow = qbf + ((size_t)bh * SEQ + t0 + wid * 16 + r16) * HEAD_DIM;
#pragma unroll
    for (int ks = 0; ks < 2; ++ks) {
      const int d0 = 32 * ks + 4 * g;
      const short4v qlo = *reinterpret_cast<const short4v*>(qrow + d0);
      const short4v qhi = *reinterpret_cast<const short4v*>(qrow + d0 + 16);
      const float4 ul = *reinterpret_cast<const float4*>(uu + h * HEAD_DIM + d0);
      const float4 uh = *reinterpret_cast<const float4*>(uu + h * HEAD_DIM + d0 + 16);
      const float4 wl = *reinterpret_cast<const float4*>(vv + h * HEAD_DIM + d0);
      const float4 wh = *reinterpret_cast<const float4*>(vv + h * HEAD_DIM + d0 + 16);
      const float ua[8] = {ul.x, ul.y, ul.z, ul.w, uh.x, uh.y, uh.z, uh.w};
      const float wa[8] = {wl.x, wl.y, wl.z, wl.w, wh.x, wh.y, wh.z, wh.w};
      short8v a, c;
#pragma unroll
      for (int e = 0; e < 4; ++e) {
        const float flo = bf2f((unsigned short)qlo[e]);
        const float fhi = bf2f((unsigned short)qhi[e]);
        a[e] = (short)f2bf(flo + ua[e]);
        a[e + 4] = (short)f2bf(fhi + ua[e + 4]);
        c[e] = (short)f2bf(flo + wa[e]);
        c[e + 4] = (short)f2bf(fhi + wa[e + 4]);
      }
      qu[ks] = a; qv[ks] = c;
    }
  }

  f32x4 oacc[4];
#pragma unroll
  for (int df = 0; df < 4; ++df) oacc[df] = (f32x4){0.f, 0.f, 0.f, 0.f};
  float m_r = -1e30f, l_r = 0.f;

  for (int st = 0; st <= qt; ++st) {
    const int s0 = st * 64;
    const int rel0 = t0 - s0 - 63;

    __syncthreads();  // all waves done reading previous tile

    // ---- stage K [s][d], V^T [d][s], RR window: pure b128 copies ----
    {
      const int row = tid >> 2;
      const int c16 = (tid & 3) << 4;
      const unsigned short* kr = kbase + (size_t)(s0 + row) * HEAD_DIM + c16;
      *reinterpret_cast<short8v*>(&Kl[row * 72 + c16]) =
          *reinterpret_cast<const short8v*>(kr);
      *reinterpret_cast<short8v*>(&Kl[row * 72 + c16 + 8]) =
          *reinterpret_cast<const short8v*>(kr + 8);
      const unsigned short* vr = vbase + (size_t)row * SEQ + s0 + c16;
      *reinterpret_cast<short8v*>(&Vt[row * 72 + c16]) =
          *reinterpret_cast<const short8v*>(vr);
      *reinterpret_cast<short8v*>(&Vt[row * 72 + c16 + 8]) =
          *reinterpret_cast<const short8v*>(vr + 8);
      const int jr = tid >> 1;
      const int ch = (tid & 1) << 5;
      const int rel = rel0 + jr;
      if (rel >= 0 && rel < SEQ) {
        const unsigned short* rr = rbase + (size_t)rel * HEAD_DIM + ch;
#pragma unroll
        for (int i = 0; i < 4; ++i)
          *reinterpret_cast<short8v*>(&RRl[jr * 72 + ch + 8 * i]) =
              *reinterpret_cast<const short8v*>(rr + 8 * i);
      } else {
        const short8v z = {};
#pragma unroll
        for (int i = 0; i < 4; ++i)
          *reinterpret_cast<short8v*>(&RRl[jr * 72 + ch + 8 * i]) = z;
      }
      if (tid < 64) KMl[tid] = kmask[(size_t)b * SEQ + s0 + tid] ? -1e30f : 0.f;
    }
    __syncthreads();

    // ---- S^T = K . Qu ----
    f32x4 sacc[4];
#pragma unroll
    for (int sf = 0; sf < 4; ++sf) sacc[sf] = (f32x4){0.f, 0.f, 0.f, 0.f};
#pragma unroll
    for (int sf = 0; sf < 4; ++sf)
#pragma unroll
      for (int ks = 0; ks < 2; ++ks)
        sacc[sf] = __builtin_amdgcn_mfma_f32_16x16x32_bf16(
            ldfragS(Kl, 16 * sf + r16, 72, 32 * ks, g), qu[ks], sacc[sf], 0, 0, 0);

    // ---- G^T = RR . Qv, this wave's 5-fragment j-window ----
#pragma unroll
    for (int fj = 0; fj < 5; ++fj) {
      f32x4 gacc = (f32x4){0.f, 0.f, 0.f, 0.f};
#pragma unroll
      for (int ks = 0; ks < 2; ++ks)
        gacc = __builtin_amdgcn_mfma_f32_16x16x32_bf16(
            ldfragS(RRl, 16 * (wid + fj) + r16, 72, 32 * ks, g), qv[ks], gacc, 0, 0, 0);
#pragma unroll
      for (int r = 0; r < 4; ++r)
        Gw[(16 * fj + 4 * g + r) * 18 + r16] = gacc[r];
    }
    asm volatile("s_waitcnt lgkmcnt(0)" ::: "memory");
    __builtin_amdgcn_sched_barrier(0);

    // ---- diagonal gather + mask + online softmax ----
    float scr[4][4];
    float rmax = -1e30f;
    const int tl = wid * 16 + r16;
    const bool diag = (st == qt);
#pragma unroll
    for (int sf = 0; sf < 4; ++sf) {
#pragma unroll
      for (int r = 0; r < 4; ++r) {
        const int sp = 16 * sf + 4 * g + r;
        const float bd = Gw[(63 + r16 - sp) * 18 + r16];
        float sc = (sacc[sf][r] + bd) * 0.125f + KMl[sp];
        if (diag && sp > tl) sc = -1e30f;
        scr[sf][r] = sc;
        rmax = fmaxf(rmax, sc);
      }
    }
    rmax = fmaxf(rmax, __shfl_xor(rmax, 16, 64));
    rmax = fmaxf(rmax, __shfl_xor(rmax, 32, 64));
    const float mnew = fmaxf(m_r, rmax);
    const float corr = __expf(m_r - mnew);
    m_r = mnew;
    float rsum = 0.f;
#pragma unroll
    for (int sf = 0; sf < 4; ++sf)
#pragma unroll
      for (int r = 0; r < 4; ++r) {
        const float p = __expf(scr[sf][r] - mnew);
        scr[sf][r] = p;
        rsum += p;
      }
    rsum += __shfl_xor(rsum, 16, 64);
    rsum += __shfl_xor(rsum, 32, 64);
    l_r = l_r * corr + rsum;
#pragma unroll
    for (int df = 0; df < 4; ++df)
#pragma unroll
      for (int r = 0; r < 4; ++r) oacc[df][r] *= corr;

    // ---- PV: O^T += V^T . P (P packed in-register with matching sigma) ----
#pragma unroll
    for (int c = 0; c < 2; ++c) {
      short8v pb;
#pragma unroll
      for (int e = 0; e < 4; ++e) {
        pb[e] = (short)f2bf(scr[2 * c][e]);
        pb[e + 4] = (short)f2bf(scr[2 * c + 1][e]);
      }
#pragma unroll
      for (int df = 0; df < 4; ++df)
        oacc[df] = __builtin_amdgcn_mfma_f32_16x16x32_bf16(
            ldfragS(Vt, 16 * df + r16, 72, 32 * c, g), pb, oacc[df], 0, 0, 0);
    }
  }

  // ---- epilogue: normalize, transpose via wave-private LDS, emit hi/lo ----
  const float inv = (l_r > 0.f) ? (1.0f / l_r) : 0.f;
#pragma unroll
  for (int df = 0; df < 4; ++df)
#pragma unroll
    for (int r = 0; r < 4; ++r)
      Gw[r16 * 68 + 16 * df + 4 * g + r] = oacc[df][r] * inv;
  asm volatile("s_waitcnt lgkmcnt(0)" ::: "memory");
  __builtin_amdgcn_sched_barrier(0);
  const int orow = lane >> 2;
  const int ocol = (lane & 3) * 16;
  const size_t obase =
      ((size_t)b * SEQ + t0 + wid * 16 + orow) * DIMSZ + h * HEAD_DIM + ocol;
  short8v h0, h1, l0, l1;
#pragma unroll
  for (int i = 0; i < 8; ++i) {
    unsigned short hh, ll;
    split2(Gw[orow * 68 + ocol + i], hh, ll);
    h0[i] = (short)hh; l0[i] = (short)ll;
    split2(Gw[orow * 68 + ocol + 8 + i], hh, ll);
    h1[i] = (short)hh; l1[i] = (short)ll;
  }
  *reinterpret_cast<short8v*>(aoh + obase) = h0;
  *reinterpret_cast<short8v*>(aoh + obase + 8) = h1;
  *reinterpret_cast<short8v*>(aol + obase) = l0;
  *reinterpret_cast<short8v*>(aol + obase + 8) = l1;
}

// ---------------------------------------------------------------------------
extern "C" void kernel_launch(void* const* d_in, const int* in_sizes, int n_in,
                              void* d_out, int out_size, void* d_ws, size_t ws_size,
                              hipStream_t stream) {
  const float* x = (const float*)d_in[0];
  const float* r = (const float*)d_in[1];
  const unsigned char* km = (const unsigned char*)d_in[2];
  const float* Wqkv = (const float*)d_in[3];
  const float* Wr = (const float*)d_in[4];
  const float* u = (const float*)d_in[5];
  const float* v = (const float*)d_in[6];
  const float* Wout = (const float*)d_in[7];
  const float* bout = (const float*)d_in[8];
  float* out = (float*)d_out;

  // workspace layout (bytes); high-water 75,497,472 B == proven round-3 usage
  char* ws = (char*)d_ws;
  unsigned short* x_hi  = (unsigned short*)(ws + 0);
  unsigned short* x_lo  = (unsigned short*)(ws + 8388608);
  unsigned short* wq_hi = (unsigned short*)(ws + 16777216);
  unsigned short* wq_lo = (unsigned short*)(ws + 23068672);
  unsigned short* wr_hi = (unsigned short*)(ws + 29360128);
  unsigned short* wr_lo = (unsigned short*)(ws + 31457280);
  unsigned short* wo_hi = (unsigned short*)(ws + 33554432);
  unsigned short* wo_lo = (unsigned short*)(ws + 35651584);
  unsigned short* qbf   = (unsigned short*)(ws + 37748736);
  unsigned short* kbf   = (unsigned short*)(ws + 46137344);
  unsigned short* vtb   = (unsigned short*)(ws + 54525952);
  unsigned short* rrbf  = (unsigned short*)(ws + 62914560);
  unsigned short* r_hi  = (unsigned short*)(ws + 67108864);
  unsigned short* r_lo  = (unsigned short*)(ws + 71303168);
  unsigned short* ao_hi = x_hi;  // x planes dead after qkv GEMM
  unsigned short* ao_lo = x_lo;

  k_conv_split<<<2048, 256, 0, stream>>>(x, x_hi, x_lo, (BATCH * SEQ * DIMSZ) / 4);
  k_conv_split<<<2048, 256, 0, stream>>>(r, r_hi, r_lo, (SEQ * DIMSZ) / 4);
  k_conv_wT<<<dim3(12, 64), 256, 0, stream>>>(Wqkv, wq_hi, wq_lo, 3 * DIMSZ);
  k_conv_wT<<<dim3(4, 64), 256, 0, stream>>>(Wr, wr_hi, wr_lo, DIMSZ);
  k_conv_wT<<<dim3(4, 64), 256, 0, stream>>>(Wout, wo_hi, wo_lo, DIMSZ);

  k_gemm_bf_qkv<<<dim3(24, 32), 256, 0, stream>>>(x_hi, x_lo, wq_hi, wq_lo, qbf, kbf, vtb);
  k_gemm_bf_r<<<dim3(8, 16), 256, 0, stream>>>(r_hi, r_lo, wr_hi, wr_lo, rrbf);
  k_attn_mfma<<<dim3(32, 32), 256, 0, stream>>>(qbf, kbf, vtb, rrbf, u, v, km, ao_hi, ao_lo);
  k_gemm_bf_out<<<dim3(8, 32), 256, 0, stream>>>(ao_hi, ao_lo, wo_hi, wo_lo, bout, out);
}

// Round 8
// 468.108 us; speedup vs baseline: 4.6635x; 1.0156x over previous
//
#include <hip/hip_runtime.h>
#include <hip/hip_bf16.h>

#define DIMSZ 1024
#define HEADS 16
#define HEAD_DIM 64
#define BATCH 2
#define SEQ 2048
#define KDIM 1024

typedef __attribute__((ext_vector_type(4))) short short4v;
typedef __attribute__((ext_vector_type(8))) short short8v;
typedef __attribute__((ext_vector_type(4))) float f32x4;

__device__ __forceinline__ unsigned short f2bf(float f) {
  unsigned int u = __float_as_uint(f);
  u += 0x7fffu + ((u >> 16) & 1u);
  return (unsigned short)(u >> 16);
}
__device__ __forceinline__ float bf2f(unsigned short h) {
  return __uint_as_float(((unsigned int)h) << 16);
}
__device__ __forceinline__ void split2(float f, unsigned short& h, unsigned short& l) {
  h = f2bf(f);
  l = f2bf(f - bf2f(h));
}

// Fragment load with sigma mapping: element e (k-group g) holds
// k = k0 + 4g + (e&3) + 16*(e>>2). Same permutation for A, B and P operands,
// so the contraction is invariant to the HW k-mapping (proven round 3).
__device__ __forceinline__ short8v ldfragS(const unsigned short* base, int row, int stride,
                                           int k0, int g) {
  const short4v lo = *reinterpret_cast<const short4v*>(base + row * stride + k0 + 4 * g);
  const short4v hi = *reinterpret_cast<const short4v*>(base + row * stride + k0 + 16 + 4 * g);
  return __builtin_shufflevector(lo, hi, 0, 1, 2, 3, 4, 5, 6, 7);
}

// ---------------------------------------------------------------------------
// Conversion: fp32 -> (hi, lo) bf16 planes (same layout)
// ---------------------------------------------------------------------------
__global__ __launch_bounds__(256) void k_conv_split(const float* __restrict__ in,
                                                    unsigned short* __restrict__ hi,
                                                    unsigned short* __restrict__ lo,
                                                    int n4) {
  int idx = blockIdx.x * 256 + threadIdx.x;
  const int stride = gridDim.x * 256;
  for (; idx < n4; idx += stride) {
    const float4 f = reinterpret_cast<const float4*>(in)[idx];
    short4v h4, l4;
    unsigned short h, l;
    split2(f.x, h, l); h4[0] = (short)h; l4[0] = (short)l;
    split2(f.y, h, l); h4[1] = (short)h; l4[1] = (short)l;
    split2(f.z, h, l); h4[2] = (short)h; l4[2] = (short)l;
    split2(f.w, h, l); h4[3] = (short)h; l4[3] = (short)l;
    reinterpret_cast<short4v*>(hi)[idx] = h4;
    reinterpret_cast<short4v*>(lo)[idx] = l4;
  }
}

// ---------------------------------------------------------------------------
// Conversion: W [KDIM][N] fp32 -> transposed (hi, lo) planes [N][KDIM] bf16
// ---------------------------------------------------------------------------
__global__ __launch_bounds__(256) void k_conv_wT(const float* __restrict__ W,
                                                 unsigned short* __restrict__ th,
                                                 unsigned short* __restrict__ tl,
                                                 int N) {
  const int n = blockIdx.x * 256 + threadIdx.x;
  const int k0 = blockIdx.y * 16;
  unsigned short h16[16], l16[16];
#pragma unroll
  for (int i = 0; i < 16; ++i)
    split2(W[(size_t)(k0 + i) * N + n], h16[i], l16[i]);
  short8v o;
  unsigned short* dh = th + (size_t)n * KDIM + k0;
  unsigned short* dl = tl + (size_t)n * KDIM + k0;
#pragma unroll
  for (int i = 0; i < 8; ++i) o[i] = (short)h16[i];
  *reinterpret_cast<short8v*>(dh) = o;
#pragma unroll
  for (int i = 0; i < 8; ++i) o[i] = (short)h16[8 + i];
  *reinterpret_cast<short8v*>(dh + 8) = o;
#pragma unroll
  for (int i = 0; i < 8; ++i) o[i] = (short)l16[i];
  *reinterpret_cast<short8v*>(dl) = o;
#pragma unroll
  for (int i = 0; i < 8; ++i) o[i] = (short)l16[8 + i];
  *reinterpret_cast<short8v*>(dl + 8) = o;
}

// ---------------------------------------------------------------------------
// Split-bf16 MFMA GEMM core: 128x128 tile, BK=32, 4 waves (2x2), 64x64/wave.
// (unchanged from round 6, verified passing)
// ---------------------------------------------------------------------------
__device__ __forceinline__ void split_gemm_core(const unsigned short* __restrict__ Ah,
                                                const unsigned short* __restrict__ Al,
                                                const unsigned short* __restrict__ Bh,
                                                const unsigned short* __restrict__ Bl,
                                                int m0, int n0, unsigned short* sm,
                                                f32x4 acc[4][4]) {
  unsigned short* sAh = sm;
  unsigned short* sAl = sm + 5120;
  unsigned short* sBh = sm + 10240;
  unsigned short* sBl = sm + 15360;
  const int tid = threadIdx.x;
  const int lane = tid & 63, wid = tid >> 6;
  const int g = lane >> 4, r16 = lane & 15;
  const int wm = wid >> 1, wn = wid & 1;
  const int srow = tid >> 1, sh16 = (tid & 1) * 16;
  const size_t aoff = (size_t)(m0 + srow) * KDIM + sh16;
  const size_t boff = (size_t)(n0 + srow) * KDIM + sh16;
  const int sws = srow * 40 + sh16;

  short8v ah0 = *reinterpret_cast<const short8v*>(Ah + aoff);
  short8v ah1 = *reinterpret_cast<const short8v*>(Ah + aoff + 8);
  short8v al0 = *reinterpret_cast<const short8v*>(Al + aoff);
  short8v al1 = *reinterpret_cast<const short8v*>(Al + aoff + 8);
  short8v bh0 = *reinterpret_cast<const short8v*>(Bh + boff);
  short8v bh1 = *reinterpret_cast<const short8v*>(Bh + boff + 8);
  short8v bl0 = *reinterpret_cast<const short8v*>(Bl + boff);
  short8v bl1 = *reinterpret_cast<const short8v*>(Bl + boff + 8);

  for (int k0 = 0; k0 < KDIM; k0 += 32) {
    __syncthreads();
    *reinterpret_cast<short8v*>(sAh + sws) = ah0;
    *reinterpret_cast<short8v*>(sAh + sws + 8) = ah1;
    *reinterpret_cast<short8v*>(sAl + sws) = al0;
    *reinterpret_cast<short8v*>(sAl + sws + 8) = al1;
    *reinterpret_cast<short8v*>(sBh + sws) = bh0;
    *reinterpret_cast<short8v*>(sBh + sws + 8) = bh1;
    *reinterpret_cast<short8v*>(sBl + sws) = bl0;
    *reinterpret_cast<short8v*>(sBl + sws + 8) = bl1;
    __syncthreads();
    if (k0 + 32 < KDIM) {  // prefetch next tile under this tile's MFMA
      ah0 = *reinterpret_cast<const short8v*>(Ah + aoff + k0 + 32);
      ah1 = *reinterpret_cast<const short8v*>(Ah + aoff + k0 + 40);
      al0 = *reinterpret_cast<const short8v*>(Al + aoff + k0 + 32);
      al1 = *reinterpret_cast<const short8v*>(Al + aoff + k0 + 40);
      bh0 = *reinterpret_cast<const short8v*>(Bh + boff + k0 + 32);
      bh1 = *reinterpret_cast<const short8v*>(Bh + boff + k0 + 40);
      bl0 = *reinterpret_cast<const short8v*>(Bl + boff + k0 + 32);
      bl1 = *reinterpret_cast<const short8v*>(Bl + boff + k0 + 40);
    }
    short8v fah[4], fal[4], fbh[4], fbl[4];
#pragma unroll
    for (int i = 0; i < 4; ++i) {
      fah[i] = ldfragS(sAh, wm * 64 + i * 16 + r16, 40, 0, g);
      fal[i] = ldfragS(sAl, wm * 64 + i * 16 + r16, 40, 0, g);
      fbh[i] = ldfragS(sBh, wn * 64 + i * 16 + r16, 40, 0, g);
      fbl[i] = ldfragS(sBl, wn * 64 + i * 16 + r16, 40, 0, g);
    }
#pragma unroll
    for (int mf = 0; mf < 4; ++mf)
#pragma unroll
      for (int nf = 0; nf < 4; ++nf) {
        acc[mf][nf] = __builtin_amdgcn_mfma_f32_16x16x32_bf16(fah[mf], fbh[nf], acc[mf][nf], 0, 0, 0);
        acc[mf][nf] = __builtin_amdgcn_mfma_f32_16x16x32_bf16(fah[mf], fbl[nf], acc[mf][nf], 0, 0, 0);
        acc[mf][nf] = __builtin_amdgcn_mfma_f32_16x16x32_bf16(fal[mf], fbh[nf], acc[mf][nf], 0, 0, 0);
      }
  }
  __syncthreads();  // LDS free for epilogue scratch reuse
}

#define GEMM_PROLOG                                        \
  __shared__ __align__(16) unsigned short sm[20480];       \
  f32x4 acc[4][4];                                         \
  _Pragma("unroll") for (int i = 0; i < 4; ++i)            \
      _Pragma("unroll") for (int j = 0; j < 4; ++j)        \
          acc[i][j] = (f32x4){0.f, 0.f, 0.f, 0.f};         \
  const int n0 = blockIdx.x * 128;                         \
  const int m0 = blockIdx.y * 128;                         \
  const int tid = threadIdx.x;                             \
  const int lane = tid & 63, wid = tid >> 6;               \
  const int g = lane >> 4, r16 = lane & 15;                \
  const int wm = wid >> 1, wn = wid & 1;

// ---------------------------------------------------------------------------
// qkv GEMM (unchanged from round 6)
// ---------------------------------------------------------------------------
__global__ __launch_bounds__(256) void k_gemm_bf_qkv(
    const unsigned short* __restrict__ Xh, const unsigned short* __restrict__ Xl,
    const unsigned short* __restrict__ Wh, const unsigned short* __restrict__ Wl,
    unsigned short* __restrict__ qbf, unsigned short* __restrict__ kbf,
    unsigned short* __restrict__ vtb) {
  GEMM_PROLOG
  split_gemm_core(Xh, Xl, Wh, Wl, m0, n0, sm, acc);

  const int n_w = n0 + wn * 64;
  const int comp = n_w >> 10;
  const int h = (n_w >> 6) & 15;
  if (comp == 2) {
#pragma unroll
    for (int mf = 0; mf < 4; ++mf) {
      const int m = m0 + wm * 64 + mf * 16 + 4 * g;
      const int b = m >> 11, t = m & (SEQ - 1);
#pragma unroll
      for (int nf = 0; nf < 4; ++nf) {
        const int d = nf * 16 + r16;
        short4v p;
#pragma unroll
        for (int r = 0; r < 4; ++r) p[r] = (short)f2bf(acc[mf][nf][r]);
        *reinterpret_cast<short4v*>(
            vtb + ((size_t)(b * HEADS + h) * HEAD_DIM + d) * SEQ + t) = p;
      }
    }
  } else {
    unsigned short* dst = comp ? kbf : qbf;
    float* scr = reinterpret_cast<float*>(sm) + wid * 1088;  // per-wave 16x68
    const int rr_ = lane >> 2, cc = (lane & 3) * 16;
    for (int mf = 0; mf < 4; ++mf) {
#pragma unroll
      for (int nf = 0; nf < 4; ++nf)
#pragma unroll
        for (int r = 0; r < 4; ++r)
          scr[(4 * g + r) * 68 + nf * 16 + r16] = acc[mf][nf][r];
      asm volatile("s_waitcnt lgkmcnt(0)" ::: "memory");
      __builtin_amdgcn_sched_barrier(0);
      const int m = m0 + wm * 64 + mf * 16 + rr_;
      const int b = m >> 11, t = m & (SEQ - 1);
      unsigned short* drow = dst + ((size_t)(b * HEADS + h) * SEQ + t) * HEAD_DIM + cc;
      short8v o0, o1;
#pragma unroll
      for (int i = 0; i < 8; ++i) {
        o0[i] = (short)f2bf(scr[rr_ * 68 + cc + i]);
        o1[i] = (short)f2bf(scr[rr_ * 68 + cc + 8 + i]);
      }
      *reinterpret_cast<short8v*>(drow) = o0;
      *reinterpret_cast<short8v*>(drow + 8) = o1;
      asm volatile("s_waitcnt lgkmcnt(0)" ::: "memory");
      __builtin_amdgcn_sched_barrier(0);
    }
  }
}

// ---------------------------------------------------------------------------
// r GEMM (unchanged from round 6)
// ---------------------------------------------------------------------------
__global__ __launch_bounds__(256) void k_gemm_bf_r(
    const unsigned short* __restrict__ Rh, const unsigned short* __restrict__ Rl,
    const unsigned short* __restrict__ Wh, const unsigned short* __restrict__ Wl,
    unsigned short* __restrict__ rrbf) {
  GEMM_PROLOG
  split_gemm_core(Rh, Rl, Wh, Wl, m0, n0, sm, acc);

  const int n_w = n0 + wn * 64;
  const int h = n_w >> 6;
  float* scr = reinterpret_cast<float*>(sm) + wid * 1088;
  const int rr_ = lane >> 2, cc = (lane & 3) * 16;
  for (int mf = 0; mf < 4; ++mf) {
#pragma unroll
    for (int nf = 0; nf < 4; ++nf)
#pragma unroll
      for (int r = 0; r < 4; ++r)
        scr[(4 * g + r) * 68 + nf * 16 + r16] = acc[mf][nf][r];
    asm volatile("s_waitcnt lgkmcnt(0)" ::: "memory");
    __builtin_amdgcn_sched_barrier(0);
    const int s = m0 + wm * 64 + mf * 16 + rr_;
    const int rel = (SEQ - 1) - s;
    unsigned short* drow = rrbf + ((size_t)h * SEQ + rel) * HEAD_DIM + cc;
    short8v o0, o1;
#pragma unroll
    for (int i = 0; i < 8; ++i) {
      o0[i] = (short)f2bf(scr[rr_ * 68 + cc + i]);
      o1[i] = (short)f2bf(scr[rr_ * 68 + cc + 8 + i]);
    }
    *reinterpret_cast<short8v*>(drow) = o0;
    *reinterpret_cast<short8v*>(drow + 8) = o1;
    asm volatile("s_waitcnt lgkmcnt(0)" ::: "memory");
    __builtin_amdgcn_sched_barrier(0);
  }
}

// ---------------------------------------------------------------------------
// out GEMM (unchanged from round 6)
// ---------------------------------------------------------------------------
__global__ __launch_bounds__(256) void k_gemm_bf_out(
    const unsigned short* __restrict__ Ah, const unsigned short* __restrict__ Al,
    const unsigned short* __restrict__ Wh, const unsigned short* __restrict__ Wl,
    const float* __restrict__ bout, float* __restrict__ out) {
  GEMM_PROLOG
  split_gemm_core(Ah, Al, Wh, Wl, m0, n0, sm, acc);

  const int n_w = n0 + wn * 64;
  float* scr = reinterpret_cast<float*>(sm) + wid * 1088;
  const int rr_ = lane >> 2, cc = (lane & 3) * 16;
  for (int mf = 0; mf < 4; ++mf) {
#pragma unroll
    for (int nf = 0; nf < 4; ++nf)
#pragma unroll
      for (int r = 0; r < 4; ++r)
        scr[(4 * g + r) * 68 + nf * 16 + r16] = acc[mf][nf][r];
    asm volatile("s_waitcnt lgkmcnt(0)" ::: "memory");
    __builtin_amdgcn_sched_barrier(0);
    const int m = m0 + wm * 64 + mf * 16 + rr_;
    float* orow = out + (size_t)m * DIMSZ + n_w + cc;
#pragma unroll
    for (int c4 = 0; c4 < 4; ++c4) {
      const float4 bias = *reinterpret_cast<const float4*>(&bout[n_w + cc + 4 * c4]);
      float4 o;
      o.x = scr[rr_ * 68 + cc + 4 * c4 + 0] + bias.x;
      o.y = scr[rr_ * 68 + cc + 4 * c4 + 1] + bias.y;
      o.z = scr[rr_ * 68 + cc + 4 * c4 + 2] + bias.z;
      o.w = scr[rr_ * 68 + cc + 4 * c4 + 3] + bias.w;
      *reinterpret_cast<float4*>(orow + 4 * c4) = o;
    }
    asm volatile("s_waitcnt lgkmcnt(0)" ::: "memory");
    __builtin_amdgcn_sched_barrier(0);
  }
}

// ---------------------------------------------------------------------------
// MFMA flash attention v3:
//  - T14 async-STAGE: tile st+1's K/V/RR/kmask prefetched into registers right
//    after barrier B, so HBM latency hides under tile st's compute. The next
//    iteration's LDS-write is the natural vmcnt wait point.
//  - LDS 60.4 -> 48.6 KB (wave-private G scratch in bf16) => 3 blocks/CU.
// ---------------------------------------------------------------------------
__global__ __launch_bounds__(256) void k_attn_mfma(const unsigned short* __restrict__ qbf,
                                                   const unsigned short* __restrict__ kbf,
                                                   const unsigned short* __restrict__ vtb,
                                                   const unsigned short* __restrict__ rrbf,
                                                   const float* __restrict__ uu,
                                                   const float* __restrict__ vv,
                                                   const unsigned char* __restrict__ kmask,
                                                   unsigned short* __restrict__ aoh,
                                                   unsigned short* __restrict__ aol) {
  // packed LDS: Kl[64][72] | Vt[64][72] | RRl[128][72] | GwH 4x[80][18] | KMl[64]f
  __shared__ __align__(16) unsigned short SM[24320];  // 48640 B
  unsigned short* Kl  = SM;
  unsigned short* Vt  = SM + 4608;
  unsigned short* RRl = SM + 9216;
  float* KMl = reinterpret_cast<float*>(SM + 24192);

  const int tid = threadIdx.x;
  const int wid = tid >> 6;
  const int lane = tid & 63;
  const int g = lane >> 4;
  const int r16 = lane & 15;
  const int qt = blockIdx.x, bh = blockIdx.y;
  const int b = bh >> 4, h = bh & 15;
  const int t0 = qt * 64;
  unsigned short* GwH = SM + 18432 + wid * 1440;  // per-wave [80][18] bf16

  const unsigned short* kbase = kbf + (size_t)bh * SEQ * HEAD_DIM;
  const unsigned short* vbase = vtb + (size_t)bh * HEAD_DIM * SEQ;
  const unsigned short* rbase = rrbf + (size_t)h * SEQ * HEAD_DIM;

  // staging geometry (constant across tiles)
  const int row = tid >> 2;            // K: s-row / V: d-row
  const int c16 = (tid & 3) << 4;
  const int jr = tid >> 1;             // RR row
  const int ch = (tid & 1) << 5;

  // ---- hoist Q fragments, adding u and v in fp32 ----
  short8v qu[2], qv[2];
  {
    const unsigned short* qrow = qbf + ((size_t)bh * SEQ + t0 + wid * 16 + r16) * HEAD_DIM;
#pragma unroll
    for (int ks = 0; ks < 2; ++ks) {
      const int d0 = 32 * ks + 4 * g;
      const short4v qlo = *reinterpret_cast<const short4v*>(qrow + d0);
      const short4v qhi = *reinterpret_cast<const short4v*>(qrow + d0 + 16);
      const float4 ul = *reinterpret_cast<const float4*>(uu + h * HEAD_DIM + d0);
      const float4 uh = *reinterpret_cast<const float4*>(uu + h * HEAD_DIM + d0 + 16);
      const float4 wl = *reinterpret_cast<const float4*>(vv + h * HEAD_DIM + d0);
      const float4 wh = *reinterpret_cast<const float4*>(vv + h * HEAD_DIM + d0 + 16);
      const float ua[8] = {ul.x, ul.y, ul.z, ul.w, uh.x, uh.y, uh.z, uh.w};
      const float wa[8] = {wl.x, wl.y, wl.z, wl.w, wh.x, wh.y, wh.z, wh.w};
      short8v a, c;
#pragma unroll
      for (int e = 0; e < 4; ++e) {
        const float flo = bf2f((unsigned short)qlo[e]);
        const float fhi = bf2f((unsigned short)qhi[e]);
        a[e] = (short)f2bf(flo + ua[e]);
        a[e + 4] = (short)f2bf(fhi + ua[e + 4]);
        c[e] = (short)f2bf(flo + wa[e]);
        c[e + 4] = (short)f2bf(fhi + wa[e + 4]);
      }
      qu[ks] = a; qv[ks] = c;
    }
  }

  // prefetch registers (named, static — rule #20)
  short8v pK0, pK1, pV0, pV1, pR0, pR1, pR2, pR3;
  unsigned char pM = 0;
  auto LOAD = [&](int st) {
    const int s0 = st * 64;
    const unsigned short* kr = kbase + (size_t)(s0 + row) * HEAD_DIM + c16;
    pK0 = *reinterpret_cast<const short8v*>(kr);
    pK1 = *reinterpret_cast<const short8v*>(kr + 8);
    const unsigned short* vr = vbase + (size_t)row * SEQ + s0 + c16;
    pV0 = *reinterpret_cast<const short8v*>(vr);
    pV1 = *reinterpret_cast<const short8v*>(vr + 8);
    const int rel = (t0 - s0 - 63) + jr;
    if (rel >= 0 && rel < SEQ) {
      const unsigned short* rr = rbase + (size_t)rel * HEAD_DIM + ch;
      pR0 = *reinterpret_cast<const short8v*>(rr);
      pR1 = *reinterpret_cast<const short8v*>(rr + 8);
      pR2 = *reinterpret_cast<const short8v*>(rr + 16);
      pR3 = *reinterpret_cast<const short8v*>(rr + 24);
    } else {
      const short8v z = {};
      pR0 = z; pR1 = z; pR2 = z; pR3 = z;
    }
    if (tid < 64) pM = kmask[(size_t)b * SEQ + s0 + tid];
  };

  f32x4 oacc[4];
#pragma unroll
  for (int df = 0; df < 4; ++df) oacc[df] = (f32x4){0.f, 0.f, 0.f, 0.f};
  float m_r = -1e30f, l_r = 0.f;

  LOAD(0);
  for (int st = 0; st <= qt; ++st) {
    __syncthreads();  // (A) all waves done reading previous tile's LDS

    // ---- write prefetched regs -> LDS (vmcnt wait folds in here) ----
    *reinterpret_cast<short8v*>(&Kl[row * 72 + c16]) = pK0;
    *reinterpret_cast<short8v*>(&Kl[row * 72 + c16 + 8]) = pK1;
    *reinterpret_cast<short8v*>(&Vt[row * 72 + c16]) = pV0;
    *reinterpret_cast<short8v*>(&Vt[row * 72 + c16 + 8]) = pV1;
    *reinterpret_cast<short8v*>(&RRl[jr * 72 + ch]) = pR0;
    *reinterpret_cast<short8v*>(&RRl[jr * 72 + ch + 8]) = pR1;
    *reinterpret_cast<short8v*>(&RRl[jr * 72 + ch + 16]) = pR2;
    *reinterpret_cast<short8v*>(&RRl[jr * 72 + ch + 24]) = pR3;
    if (tid < 64) KMl[tid] = pM ? -1e30f : 0.f;
    __syncthreads();  // (B)

    if (st < qt) LOAD(st + 1);  // T14: loads fly under this tile's compute

    // ---- S^T = K . Qu ----
    f32x4 sacc[4];
#pragma unroll
    for (int sf = 0; sf < 4; ++sf) sacc[sf] = (f32x4){0.f, 0.f, 0.f, 0.f};
#pragma unroll
    for (int sf = 0; sf < 4; ++sf)
#pragma unroll
      for (int ks = 0; ks < 2; ++ks)
        sacc[sf] = __builtin_amdgcn_mfma_f32_16x16x32_bf16(
            ldfragS(Kl, 16 * sf + r16, 72, 32 * ks, g), qu[ks], sacc[sf], 0, 0, 0);

    // ---- G^T = RR . Qv, this wave's 5-fragment j-window (bf16 scratch) ----
#pragma unroll
    for (int fj = 0; fj < 5; ++fj) {
      f32x4 gacc = (f32x4){0.f, 0.f, 0.f, 0.f};
#pragma unroll
      for (int ks = 0; ks < 2; ++ks)
        gacc = __builtin_amdgcn_mfma_f32_16x16x32_bf16(
            ldfragS(RRl, 16 * (wid + fj) + r16, 72, 32 * ks, g), qv[ks], gacc, 0, 0, 0);
#pragma unroll
      for (int r = 0; r < 4; ++r)
        GwH[(16 * fj + 4 * g + r) * 18 + r16] = f2bf(gacc[r]);
    }
    asm volatile("s_waitcnt lgkmcnt(0)" ::: "memory");
    __builtin_amdgcn_sched_barrier(0);

    // ---- diagonal gather + mask + online softmax ----
    float scr[4][4];
    float rmax = -1e30f;
    const int tl = wid * 16 + r16;
    const bool diag = (st == qt);
#pragma unroll
    for (int sf = 0; sf < 4; ++sf) {
#pragma unroll
      for (int r = 0; r < 4; ++r) {
        const int sp = 16 * sf + 4 * g + r;
        const float bd = bf2f(GwH[(63 + r16 - sp) * 18 + r16]);
        float sc = (sacc[sf][r] + bd) * 0.125f + KMl[sp];
        if (diag && sp > tl) sc = -1e30f;
        scr[sf][r] = sc;
        rmax = fmaxf(rmax, sc);
      }
    }
    rmax = fmaxf(rmax, __shfl_xor(rmax, 16, 64));
    rmax = fmaxf(rmax, __shfl_xor(rmax, 32, 64));
    const float mnew = fmaxf(m_r, rmax);
    const float corr = __expf(m_r - mnew);
    m_r = mnew;
    float rsum = 0.f;
#pragma unroll
    for (int sf = 0; sf < 4; ++sf)
#pragma unroll
      for (int r = 0; r < 4; ++r) {
        const float p = __expf(scr[sf][r] - mnew);
        scr[sf][r] = p;
        rsum += p;
      }
    rsum += __shfl_xor(rsum, 16, 64);
    rsum += __shfl_xor(rsum, 32, 64);
    l_r = l_r * corr + rsum;
#pragma unroll
    for (int df = 0; df < 4; ++df)
#pragma unroll
      for (int r = 0; r < 4; ++r) oacc[df][r] *= corr;

    // ---- PV: O^T += V^T . P (P packed in-register with matching sigma) ----
#pragma unroll
    for (int c = 0; c < 2; ++c) {
      short8v pb;
#pragma unroll
      for (int e = 0; e < 4; ++e) {
        pb[e] = (short)f2bf(scr[2 * c][e]);
        pb[e + 4] = (short)f2bf(scr[2 * c + 1][e]);
      }
#pragma unroll
      for (int df = 0; df < 4; ++df)
        oacc[df] = __builtin_amdgcn_mfma_f32_16x16x32_bf16(
            ldfragS(Vt, 16 * df + r16, 72, 32 * c, g), pb, oacc[df], 0, 0, 0);
    }
  }

  // ---- epilogue: barrier (Vt reads done), reuse K/V LDS as fp32 scratch ----
  __syncthreads();
  float* scr2 = reinterpret_cast<float*>(SM) + wid * 1088;  // 16x68 per wave
  const float inv = (l_r > 0.f) ? (1.0f / l_r) : 0.f;
#pragma unroll
  for (int df = 0; df < 4; ++df)
#pragma unroll
    for (int r = 0; r < 4; ++r)
      scr2[r16 * 68 + 16 * df + 4 * g + r] = oacc[df][r] * inv;
  asm volatile("s_waitcnt lgkmcnt(0)" ::: "memory");
  __builtin_amdgcn_sched_barrier(0);
  const int orow = lane >> 2;
  const int ocol = (lane & 3) * 16;
  const size_t obase =
      ((size_t)b * SEQ + t0 + wid * 16 + orow) * DIMSZ + h * HEAD_DIM + ocol;
  short8v h0, h1, l0, l1;
#pragma unroll
  for (int i = 0; i < 8; ++i) {
    unsigned short hh, ll;
    split2(scr2[orow * 68 + ocol + i], hh, ll);
    h0[i] = (short)hh; l0[i] = (short)ll;
    split2(scr2[orow * 68 + ocol + 8 + i], hh, ll);
    h1[i] = (short)hh; l1[i] = (short)ll;
  }
  *reinterpret_cast<short8v*>(aoh + obase) = h0;
  *reinterpret_cast<short8v*>(aoh + obase + 8) = h1;
  *reinterpret_cast<short8v*>(aol + obase) = l0;
  *reinterpret_cast<short8v*>(aol + obase + 8) = l1;
}

// ---------------------------------------------------------------------------
extern "C" void kernel_launch(void* const* d_in, const int* in_sizes, int n_in,
                              void* d_out, int out_size, void* d_ws, size_t ws_size,
                              hipStream_t stream) {
  const float* x = (const float*)d_in[0];
  const float* r = (const float*)d_in[1];
  const unsigned char* km = (const unsigned char*)d_in[2];
  const float* Wqkv = (const float*)d_in[3];
  const float* Wr = (const float*)d_in[4];
  const float* u = (const float*)d_in[5];
  const float* v = (const float*)d_in[6];
  const float* Wout = (const float*)d_in[7];
  const float* bout = (const float*)d_in[8];
  float* out = (float*)d_out;

  // workspace layout (bytes); high-water 75,497,472 B (proven)
  char* ws = (char*)d_ws;
  unsigned short* x_hi  = (unsigned short*)(ws + 0);
  unsigned short* x_lo  = (unsigned short*)(ws + 8388608);
  unsigned short* wq_hi = (unsigned short*)(ws + 16777216);
  unsigned short* wq_lo = (unsigned short*)(ws + 23068672);
  unsigned short* wr_hi = (unsigned short*)(ws + 29360128);
  unsigned short* wr_lo = (unsigned short*)(ws + 31457280);
  unsigned short* wo_hi = (unsigned short*)(ws + 33554432);
  unsigned short* wo_lo = (unsigned short*)(ws + 35651584);
  unsigned short* qbf   = (unsigned short*)(ws + 37748736);
  unsigned short* kbf   = (unsigned short*)(ws + 46137344);
  unsigned short* vtb   = (unsigned short*)(ws + 54525952);
  unsigned short* rrbf  = (unsigned short*)(ws + 62914560);
  unsigned short* r_hi  = (unsigned short*)(ws + 67108864);
  unsigned short* r_lo  = (unsigned short*)(ws + 71303168);
  unsigned short* ao_hi = x_hi;  // x planes dead after qkv GEMM
  unsigned short* ao_lo = x_lo;

  k_conv_split<<<2048, 256, 0, stream>>>(x, x_hi, x_lo, (BATCH * SEQ * DIMSZ) / 4);
  k_conv_split<<<2048, 256, 0, stream>>>(r, r_hi, r_lo, (SEQ * DIMSZ) / 4);
  k_conv_wT<<<dim3(12, 64), 256, 0, stream>>>(Wqkv, wq_hi, wq_lo, 3 * DIMSZ);
  k_conv_wT<<<dim3(4, 64), 256, 0, stream>>>(Wr, wr_hi, wr_lo, DIMSZ);
  k_conv_wT<<<dim3(4, 64), 256, 0, stream>>>(Wout, wo_hi, wo_lo, DIMSZ);

  k_gemm_bf_qkv<<<dim3(24, 32), 256, 0, stream>>>(x_hi, x_lo, wq_hi, wq_lo, qbf, kbf, vtb);
  k_gemm_bf_r<<<dim3(8, 16), 256, 0, stream>>>(r_hi, r_lo, wr_hi, wr_lo, rrbf);
  k_attn_mfma<<<dim3(32, 32), 256, 0, stream>>>(qbf, kbf, vtb, rrbf, u, v, km, ao_hi, ao_lo);
  k_gemm_bf_out<<<dim3(8, 32), 256, 0, stream>>>(ao_hi, ao_lo, wo_hi, wo_lo, bout, out);
}

// Round 10
// 388.619 us; speedup vs baseline: 5.6174x; 1.2045x over previous
//
#include <hip/hip_runtime.h>
#include <hip/hip_bf16.h>

#define DIMSZ 1024
#define HEADS 16
#define HEAD_DIM 64
#define BATCH 2
#define SEQ 2048
#define KDIM 1024

typedef __attribute__((ext_vector_type(4))) short short4v;
typedef __attribute__((ext_vector_type(8))) short short8v;
typedef __attribute__((ext_vector_type(4))) float f32x4;

__device__ __forceinline__ unsigned short f2bf(float f) {
  unsigned int u = __float_as_uint(f);
  u += 0x7fffu + ((u >> 16) & 1u);
  return (unsigned short)(u >> 16);
}
__device__ __forceinline__ float bf2f(unsigned short h) {
  return __uint_as_float(((unsigned int)h) << 16);
}
__device__ __forceinline__ void split2(float f, unsigned short& h, unsigned short& l) {
  h = f2bf(f);
  l = f2bf(f - bf2f(h));
}

// Fragment load with sigma mapping: element e (k-group g) holds
// k = k0 + 4g + (e&3) + 16*(e>>2). Same permutation for A, B and P operands,
// so the contraction is invariant to the HW k-mapping (proven round 3).
__device__ __forceinline__ short8v ldfragS(const unsigned short* base, int row, int stride,
                                           int k0, int g) {
  const short4v lo = *reinterpret_cast<const short4v*>(base + row * stride + k0 + 4 * g);
  const short4v hi = *reinterpret_cast<const short4v*>(base + row * stride + k0 + 16 + 4 * g);
  return __builtin_shufflevector(lo, hi, 0, 1, 2, 3, 4, 5, 6, 7);
}

// ---------------------------------------------------------------------------
// Conversion: fp32 -> (hi, lo) bf16 planes (same layout)
// ---------------------------------------------------------------------------
__global__ __launch_bounds__(256) void k_conv_split(const float* __restrict__ in,
                                                    unsigned short* __restrict__ hi,
                                                    unsigned short* __restrict__ lo,
                                                    int n4) {
  int idx = blockIdx.x * 256 + threadIdx.x;
  const int stride = gridDim.x * 256;
  for (; idx < n4; idx += stride) {
    const float4 f = reinterpret_cast<const float4*>(in)[idx];
    short4v h4, l4;
    unsigned short h, l;
    split2(f.x, h, l); h4[0] = (short)h; l4[0] = (short)l;
    split2(f.y, h, l); h4[1] = (short)h; l4[1] = (short)l;
    split2(f.z, h, l); h4[2] = (short)h; l4[2] = (short)l;
    split2(f.w, h, l); h4[3] = (short)h; l4[3] = (short)l;
    reinterpret_cast<short4v*>(hi)[idx] = h4;
    reinterpret_cast<short4v*>(lo)[idx] = l4;
  }
}

// ---------------------------------------------------------------------------
// Conversion: W [KDIM][N] fp32 -> transposed (hi, lo) planes [N][KDIM] bf16
// ---------------------------------------------------------------------------
__global__ __launch_bounds__(256) void k_conv_wT(const float* __restrict__ W,
                                                 unsigned short* __restrict__ th,
                                                 unsigned short* __restrict__ tl,
                                                 int N) {
  const int n = blockIdx.x * 256 + threadIdx.x;
  const int k0 = blockIdx.y * 16;
  unsigned short h16[16], l16[16];
#pragma unroll
  for (int i = 0; i < 16; ++i)
    split2(W[(size_t)(k0 + i) * N + n], h16[i], l16[i]);
  short8v o;
  unsigned short* dh = th + (size_t)n * KDIM + k0;
  unsigned short* dl = tl + (size_t)n * KDIM + k0;
#pragma unroll
  for (int i = 0; i < 8; ++i) o[i] = (short)h16[i];
  *reinterpret_cast<short8v*>(dh) = o;
#pragma unroll
  for (int i = 0; i < 8; ++i) o[i] = (short)h16[8 + i];
  *reinterpret_cast<short8v*>(dh + 8) = o;
#pragma unroll
  for (int i = 0; i < 8; ++i) o[i] = (short)l16[i];
  *reinterpret_cast<short8v*>(dl) = o;
#pragma unroll
  for (int i = 0; i < 8; ++i) o[i] = (short)l16[8 + i];
  *reinterpret_cast<short8v*>(dl + 8) = o;
}

// ---------------------------------------------------------------------------
// Split-bf16 MFMA GEMM core: 128x128 tile, BK=32, 4 waves (2x2), 64x64/wave.
// (unchanged, verified passing)
// ---------------------------------------------------------------------------
__device__ __forceinline__ void split_gemm_core(const unsigned short* __restrict__ Ah,
                                                const unsigned short* __restrict__ Al,
                                                const unsigned short* __restrict__ Bh,
                                                const unsigned short* __restrict__ Bl,
                                                int m0, int n0, unsigned short* sm,
                                                f32x4 acc[4][4]) {
  unsigned short* sAh = sm;
  unsigned short* sAl = sm + 5120;
  unsigned short* sBh = sm + 10240;
  unsigned short* sBl = sm + 15360;
  const int tid = threadIdx.x;
  const int lane = tid & 63, wid = tid >> 6;
  const int g = lane >> 4, r16 = lane & 15;
  const int wm = wid >> 1, wn = wid & 1;
  const int srow = tid >> 1, sh16 = (tid & 1) * 16;
  const size_t aoff = (size_t)(m0 + srow) * KDIM + sh16;
  const size_t boff = (size_t)(n0 + srow) * KDIM + sh16;
  const int sws = srow * 40 + sh16;

  short8v ah0 = *reinterpret_cast<const short8v*>(Ah + aoff);
  short8v ah1 = *reinterpret_cast<const short8v*>(Ah + aoff + 8);
  short8v al0 = *reinterpret_cast<const short8v*>(Al + aoff);
  short8v al1 = *reinterpret_cast<const short8v*>(Al + aoff + 8);
  short8v bh0 = *reinterpret_cast<const short8v*>(Bh + boff);
  short8v bh1 = *reinterpret_cast<const short8v*>(Bh + boff + 8);
  short8v bl0 = *reinterpret_cast<const short8v*>(Bl + boff);
  short8v bl1 = *reinterpret_cast<const short8v*>(Bl + boff + 8);

  for (int k0 = 0; k0 < KDIM; k0 += 32) {
    __syncthreads();
    *reinterpret_cast<short8v*>(sAh + sws) = ah0;
    *reinterpret_cast<short8v*>(sAh + sws + 8) = ah1;
    *reinterpret_cast<short8v*>(sAl + sws) = al0;
    *reinterpret_cast<short8v*>(sAl + sws + 8) = al1;
    *reinterpret_cast<short8v*>(sBh + sws) = bh0;
    *reinterpret_cast<short8v*>(sBh + sws + 8) = bh1;
    *reinterpret_cast<short8v*>(sBl + sws) = bl0;
    *reinterpret_cast<short8v*>(sBl + sws + 8) = bl1;
    __syncthreads();
    if (k0 + 32 < KDIM) {  // prefetch next tile under this tile's MFMA
      ah0 = *reinterpret_cast<const short8v*>(Ah + aoff + k0 + 32);
      ah1 = *reinterpret_cast<const short8v*>(Ah + aoff + k0 + 40);
      al0 = *reinterpret_cast<const short8v*>(Al + aoff + k0 + 32);
      al1 = *reinterpret_cast<const short8v*>(Al + aoff + k0 + 40);
      bh0 = *reinterpret_cast<const short8v*>(Bh + boff + k0 + 32);
      bh1 = *reinterpret_cast<const short8v*>(Bh + boff + k0 + 40);
      bl0 = *reinterpret_cast<const short8v*>(Bl + boff + k0 + 32);
      bl1 = *reinterpret_cast<const short8v*>(Bl + boff + k0 + 40);
    }
    short8v fah[4], fal[4], fbh[4], fbl[4];
#pragma unroll
    for (int i = 0; i < 4; ++i) {
      fah[i] = ldfragS(sAh, wm * 64 + i * 16 + r16, 40, 0, g);
      fal[i] = ldfragS(sAl, wm * 64 + i * 16 + r16, 40, 0, g);
      fbh[i] = ldfragS(sBh, wn * 64 + i * 16 + r16, 40, 0, g);
      fbl[i] = ldfragS(sBl, wn * 64 + i * 16 + r16, 40, 0, g);
    }
#pragma unroll
    for (int mf = 0; mf < 4; ++mf)
#pragma unroll
      for (int nf = 0; nf < 4; ++nf) {
        acc[mf][nf] = __builtin_amdgcn_mfma_f32_16x16x32_bf16(fah[mf], fbh[nf], acc[mf][nf], 0, 0, 0);
        acc[mf][nf] = __builtin_amdgcn_mfma_f32_16x16x32_bf16(fah[mf], fbl[nf], acc[mf][nf], 0, 0, 0);
        acc[mf][nf] = __builtin_amdgcn_mfma_f32_16x16x32_bf16(fal[mf], fbh[nf], acc[mf][nf], 0, 0, 0);
      }
  }
  __syncthreads();  // LDS free for epilogue scratch reuse
}

#define GEMM_PROLOG                                        \
  __shared__ __align__(16) unsigned short sm[20480];       \
  f32x4 acc[4][4];                                         \
  _Pragma("unroll") for (int i = 0; i < 4; ++i)            \
      _Pragma("unroll") for (int j = 0; j < 4; ++j)        \
          acc[i][j] = (f32x4){0.f, 0.f, 0.f, 0.f};         \
  const int n0 = blockIdx.x * 128;                         \
  const int m0 = blockIdx.y * 128;                         \
  const int tid = threadIdx.x;                             \
  const int lane = tid & 63, wid = tid >> 6;               \
  const int g = lane >> 4, r16 = lane & 15;                \
  const int wm = wid >> 1, wn = wid & 1;

// ---------------------------------------------------------------------------
// qkv GEMM (unchanged)
// ---------------------------------------------------------------------------
__global__ __launch_bounds__(256) void k_gemm_bf_qkv(
    const unsigned short* __restrict__ Xh, const unsigned short* __restrict__ Xl,
    const unsigned short* __restrict__ Wh, const unsigned short* __restrict__ Wl,
    unsigned short* __restrict__ qbf, unsigned short* __restrict__ kbf,
    unsigned short* __restrict__ vtb) {
  GEMM_PROLOG
  split_gemm_core(Xh, Xl, Wh, Wl, m0, n0, sm, acc);

  const int n_w = n0 + wn * 64;
  const int comp = n_w >> 10;
  const int h = (n_w >> 6) & 15;
  if (comp == 2) {
#pragma unroll
    for (int mf = 0; mf < 4; ++mf) {
      const int m = m0 + wm * 64 + mf * 16 + 4 * g;
      const int b = m >> 11, t = m & (SEQ - 1);
#pragma unroll
      for (int nf = 0; nf < 4; ++nf) {
        const int d = nf * 16 + r16;
        short4v p;
#pragma unroll
        for (int r = 0; r < 4; ++r) p[r] = (short)f2bf(acc[mf][nf][r]);
        *reinterpret_cast<short4v*>(
            vtb + ((size_t)(b * HEADS + h) * HEAD_DIM + d) * SEQ + t) = p;
      }
    }
  } else {
    unsigned short* dst = comp ? kbf : qbf;
    float* scr = reinterpret_cast<float*>(sm) + wid * 1088;  // per-wave 16x68
    const int rr_ = lane >> 2, cc = (lane & 3) * 16;
    for (int mf = 0; mf < 4; ++mf) {
#pragma unroll
      for (int nf = 0; nf < 4; ++nf)
#pragma unroll
        for (int r = 0; r < 4; ++r)
          scr[(4 * g + r) * 68 + nf * 16 + r16] = acc[mf][nf][r];
      asm volatile("s_waitcnt lgkmcnt(0)" ::: "memory");
      __builtin_amdgcn_sched_barrier(0);
      const int m = m0 + wm * 64 + mf * 16 + rr_;
      const int b = m >> 11, t = m & (SEQ - 1);
      unsigned short* drow = dst + ((size_t)(b * HEADS + h) * SEQ + t) * HEAD_DIM + cc;
      short8v o0, o1;
#pragma unroll
      for (int i = 0; i < 8; ++i) {
        o0[i] = (short)f2bf(scr[rr_ * 68 + cc + i]);
        o1[i] = (short)f2bf(scr[rr_ * 68 + cc + 8 + i]);
      }
      *reinterpret_cast<short8v*>(drow) = o0;
      *reinterpret_cast<short8v*>(drow + 8) = o1;
      asm volatile("s_waitcnt lgkmcnt(0)" ::: "memory");
      __builtin_amdgcn_sched_barrier(0);
    }
  }
}

// ---------------------------------------------------------------------------
// r GEMM (unchanged)
// ---------------------------------------------------------------------------
__global__ __launch_bounds__(256) void k_gemm_bf_r(
    const unsigned short* __restrict__ Rh, const unsigned short* __restrict__ Rl,
    const unsigned short* __restrict__ Wh, const unsigned short* __restrict__ Wl,
    unsigned short* __restrict__ rrbf) {
  GEMM_PROLOG
  split_gemm_core(Rh, Rl, Wh, Wl, m0, n0, sm, acc);

  const int n_w = n0 + wn * 64;
  const int h = n_w >> 6;
  float* scr = reinterpret_cast<float*>(sm) + wid * 1088;
  const int rr_ = lane >> 2, cc = (lane & 3) * 16;
  for (int mf = 0; mf < 4; ++mf) {
#pragma unroll
    for (int nf = 0; nf < 4; ++nf)
#pragma unroll
      for (int r = 0; r < 4; ++r)
        scr[(4 * g + r) * 68 + nf * 16 + r16] = acc[mf][nf][r];
    asm volatile("s_waitcnt lgkmcnt(0)" ::: "memory");
    __builtin_amdgcn_sched_barrier(0);
    const int s = m0 + wm * 64 + mf * 16 + rr_;
    const int rel = (SEQ - 1) - s;
    unsigned short* drow = rrbf + ((size_t)h * SEQ + rel) * HEAD_DIM + cc;
    short8v o0, o1;
#pragma unroll
    for (int i = 0; i < 8; ++i) {
      o0[i] = (short)f2bf(scr[rr_ * 68 + cc + i]);
      o1[i] = (short)f2bf(scr[rr_ * 68 + cc + 8 + i]);
    }
    *reinterpret_cast<short8v*>(drow) = o0;
    *reinterpret_cast<short8v*>(drow + 8) = o1;
    asm volatile("s_waitcnt lgkmcnt(0)" ::: "memory");
    __builtin_amdgcn_sched_barrier(0);
  }
}

// ---------------------------------------------------------------------------
// out GEMM (unchanged)
// ---------------------------------------------------------------------------
__global__ __launch_bounds__(256) void k_gemm_bf_out(
    const unsigned short* __restrict__ Ah, const unsigned short* __restrict__ Al,
    const unsigned short* __restrict__ Wh, const unsigned short* __restrict__ Wl,
    const float* __restrict__ bout, float* __restrict__ out) {
  GEMM_PROLOG
  split_gemm_core(Ah, Al, Wh, Wl, m0, n0, sm, acc);

  const int n_w = n0 + wn * 64;
  float* scr = reinterpret_cast<float*>(sm) + wid * 1088;
  const int rr_ = lane >> 2, cc = (lane & 3) * 16;
  for (int mf = 0; mf < 4; ++mf) {
#pragma unroll
    for (int nf = 0; nf < 4; ++nf)
#pragma unroll
      for (int r = 0; r < 4; ++r)
        scr[(4 * g + r) * 68 + nf * 16 + r16] = acc[mf][nf][r];
    asm volatile("s_waitcnt lgkmcnt(0)" ::: "memory");
    __builtin_amdgcn_sched_barrier(0);
    const int m = m0 + wm * 64 + mf * 16 + rr_;
    float* orow = out + (size_t)m * DIMSZ + n_w + cc;
#pragma unroll
    for (int c4 = 0; c4 < 4; ++c4) {
      const float4 bias = *reinterpret_cast<const float4*>(&bout[n_w + cc + 4 * c4]);
      float4 o;
      o.x = scr[rr_ * 68 + cc + 4 * c4 + 0] + bias.x;
      o.y = scr[rr_ * 68 + cc + 4 * c4 + 1] + bias.y;
      o.z = scr[rr_ * 68 + cc + 4 * c4 + 2] + bias.z;
      o.w = scr[rr_ * 68 + cc + 4 * c4 + 3] + bias.w;
      *reinterpret_cast<float4*>(orow + 4 * c4) = o;
    }
    asm volatile("s_waitcnt lgkmcnt(0)" ::: "memory");
    __builtin_amdgcn_sched_barrier(0);
  }
}

// ---------------------------------------------------------------------------
// MFMA flash attention v4:
//  - T1 XCD-aware block remap: 1D grid, xcd = wgid % 8 pins 4 bh values per
//    XCD (K+V+RR working set 3 MB <= 4 MB L2) -> kills the 4x HBM re-fetch
//    (round-8 counters: FETCH 120 MB vs 28 MB unique, BW 706 GB/s = latency
//    -bound L2 misses). qt reversed within group: longest blocks first (LPT).
//  - T14 reg prefetch + 48.6 KB LDS (round 8, proven) unchanged.
// ---------------------------------------------------------------------------
__global__ __launch_bounds__(256) void k_attn_mfma(const unsigned short* __restrict__ qbf,
                                                   const unsigned short* __restrict__ kbf,
                                                   const unsigned short* __restrict__ vtb,
                                                   const unsigned short* __restrict__ rrbf,
                                                   const float* __restrict__ uu,
                                                   const float* __restrict__ vv,
                                                   const unsigned char* __restrict__ kmask,
                                                   unsigned short* __restrict__ aoh,
                                                   unsigned short* __restrict__ aol) {
  // packed LDS: Kl[64][72] | Vt[64][72] | RRl[128][72] | GwH 4x[80][18] | KMl[64]f
  __shared__ __align__(16) unsigned short SM[24320];  // 48640 B
  unsigned short* Kl  = SM;
  unsigned short* Vt  = SM + 4608;
  unsigned short* RRl = SM + 9216;
  float* KMl = reinterpret_cast<float*>(SM + 24192);

  const int tid = threadIdx.x;
  const int wid = tid >> 6;
  const int lane = tid & 63;
  const int g = lane >> 4;
  const int r16 = lane & 15;
  // T1 remap: xcd group = wgid % 8 owns bh in [4*xg, 4*xg+4); qt descending.
  const int raw = blockIdx.x;
  const int xg = raw & 7;
  const int idx = raw >> 3;          // 0..127
  const int bh = xg * 4 + (idx & 3);
  const int qt = 31 - (idx >> 2);
  const int b = bh >> 4, h = bh & 15;
  const int t0 = qt * 64;
  unsigned short* GwH = SM + 18432 + wid * 1440;  // per-wave [80][18] bf16

  const unsigned short* kbase = kbf + (size_t)bh * SEQ * HEAD_DIM;
  const unsigned short* vbase = vtb + (size_t)bh * HEAD_DIM * SEQ;
  const unsigned short* rbase = rrbf + (size_t)h * SEQ * HEAD_DIM;

  // staging geometry (constant across tiles)
  const int row = tid >> 2;            // K: s-row / V: d-row
  const int c16 = (tid & 3) << 4;
  const int jr = tid >> 1;             // RR row
  const int ch = (tid & 1) << 5;

  // ---- hoist Q fragments, adding u and v in fp32 ----
  short8v qu[2], qv[2];
  {
    const unsigned short* qrow = qbf + ((size_t)bh * SEQ + t0 + wid * 16 + r16) * HEAD_DIM;
#pragma unroll
    for (int ks = 0; ks < 2; ++ks) {
      const int d0 = 32 * ks + 4 * g;
      const short4v qlo = *reinterpret_cast<const short4v*>(qrow + d0);
      const short4v qhi = *reinterpret_cast<const short4v*>(qrow + d0 + 16);
      const float4 ul = *reinterpret_cast<const float4*>(uu + h * HEAD_DIM + d0);
      const float4 uh = *reinterpret_cast<const float4*>(uu + h * HEAD_DIM + d0 + 16);
      const float4 wl = *reinterpret_cast<const float4*>(vv + h * HEAD_DIM + d0);
      const float4 wh = *reinterpret_cast<const float4*>(vv + h * HEAD_DIM + d0 + 16);
      const float ua[8] = {ul.x, ul.y, ul.z, ul.w, uh.x, uh.y, uh.z, uh.w};
      const float wa[8] = {wl.x, wl.y, wl.z, wl.w, wh.x, wh.y, wh.z, wh.w};
      short8v a, c;
#pragma unroll
      for (int e = 0; e < 4; ++e) {
        const float flo = bf2f((unsigned short)qlo[e]);
        const float fhi = bf2f((unsigned short)qhi[e]);
        a[e] = (short)f2bf(flo + ua[e]);
        a[e + 4] = (short)f2bf(fhi + ua[e + 4]);
        c[e] = (short)f2bf(flo + wa[e]);
        c[e + 4] = (short)f2bf(fhi + wa[e + 4]);
      }
      qu[ks] = a; qv[ks] = c;
    }
  }

  // prefetch registers (named, static — rule #20)
  short8v pK0, pK1, pV0, pV1, pR0, pR1, pR2, pR3;
  unsigned char pM = 0;
  auto LOAD = [&](int st) {
    const int s0 = st * 64;
    const unsigned short* kr = kbase + (size_t)(s0 + row) * HEAD_DIM + c16;
    pK0 = *reinterpret_cast<const short8v*>(kr);
    pK1 = *reinterpret_cast<const short8v*>(kr + 8);
    const unsigned short* vr = vbase + (size_t)row * SEQ + s0 + c16;
    pV0 = *reinterpret_cast<const short8v*>(vr);
    pV1 = *reinterpret_cast<const short8v*>(vr + 8);
    const int rel = (t0 - s0 - 63) + jr;
    if (rel >= 0 && rel < SEQ) {
      const unsigned short* rr = rbase + (size_t)rel * HEAD_DIM + ch;
      pR0 = *reinterpret_cast<const short8v*>(rr);
      pR1 = *reinterpret_cast<const short8v*>(rr + 8);
      pR2 = *reinterpret_cast<const short8v*>(rr + 16);
      pR3 = *reinterpret_cast<const short8v*>(rr + 24);
    } else {
      const short8v z = {};
      pR0 = z; pR1 = z; pR2 = z; pR3 = z;
    }
    if (tid < 64) pM = kmask[(size_t)b * SEQ + s0 + tid];
  };

  f32x4 oacc[4];
#pragma unroll
  for (int df = 0; df < 4; ++df) oacc[df] = (f32x4){0.f, 0.f, 0.f, 0.f};
  float m_r = -1e30f, l_r = 0.f;

  LOAD(0);
  for (int st = 0; st <= qt; ++st) {
    __syncthreads();  // (A) all waves done reading previous tile's LDS

    // ---- write prefetched regs -> LDS (vmcnt wait folds in here) ----
    *reinterpret_cast<short8v*>(&Kl[row * 72 + c16]) = pK0;
    *reinterpret_cast<short8v*>(&Kl[row * 72 + c16 + 8]) = pK1;
    *reinterpret_cast<short8v*>(&Vt[row * 72 + c16]) = pV0;
    *reinterpret_cast<short8v*>(&Vt[row * 72 + c16 + 8]) = pV1;
    *reinterpret_cast<short8v*>(&RRl[jr * 72 + ch]) = pR0;
    *reinterpret_cast<short8v*>(&RRl[jr * 72 + ch + 8]) = pR1;
    *reinterpret_cast<short8v*>(&RRl[jr * 72 + ch + 16]) = pR2;
    *reinterpret_cast<short8v*>(&RRl[jr * 72 + ch + 24]) = pR3;
    if (tid < 64) KMl[tid] = pM ? -1e30f : 0.f;
    __syncthreads();  // (B)

    if (st < qt) LOAD(st + 1);  // T14: loads fly under this tile's compute

    // ---- S^T = K . Qu ----
    f32x4 sacc[4];
#pragma unroll
    for (int sf = 0; sf < 4; ++sf) sacc[sf] = (f32x4){0.f, 0.f, 0.f, 0.f};
#pragma unroll
    for (int sf = 0; sf < 4; ++sf)
#pragma unroll
      for (int ks = 0; ks < 2; ++ks)
        sacc[sf] = __builtin_amdgcn_mfma_f32_16x16x32_bf16(
            ldfragS(Kl, 16 * sf + r16, 72, 32 * ks, g), qu[ks], sacc[sf], 0, 0, 0);

    // ---- G^T = RR . Qv, this wave's 5-fragment j-window (bf16 scratch) ----
#pragma unroll
    for (int fj = 0; fj < 5; ++fj) {
      f32x4 gacc = (f32x4){0.f, 0.f, 0.f, 0.f};
#pragma unroll
      for (int ks = 0; ks < 2; ++ks)
        gacc = __builtin_amdgcn_mfma_f32_16x16x32_bf16(
            ldfragS(RRl, 16 * (wid + fj) + r16, 72, 32 * ks, g), qv[ks], gacc, 0, 0, 0);
#pragma unroll
      for (int r = 0; r < 4; ++r)
        GwH[(16 * fj + 4 * g + r) * 18 + r16] = f2bf(gacc[r]);
    }
    asm volatile("s_waitcnt lgkmcnt(0)" ::: "memory");
    __builtin_amdgcn_sched_barrier(0);

    // ---- diagonal gather + mask + online softmax ----
    float scr[4][4];
    float rmax = -1e30f;
    const int tl = wid * 16 + r16;
    const bool diag = (st == qt);
#pragma unroll
    for (int sf = 0; sf < 4; ++sf) {
#pragma unroll
      for (int r = 0; r < 4; ++r) {
        const int sp = 16 * sf + 4 * g + r;
        const float bd = bf2f(GwH[(63 + r16 - sp) * 18 + r16]);
        float sc = (sacc[sf][r] + bd) * 0.125f + KMl[sp];
        if (diag && sp > tl) sc = -1e30f;
        scr[sf][r] = sc;
        rmax = fmaxf(rmax, sc);
      }
    }
    rmax = fmaxf(rmax, __shfl_xor(rmax, 16, 64));
    rmax = fmaxf(rmax, __shfl_xor(rmax, 32, 64));
    const float mnew = fmaxf(m_r, rmax);
    const float corr = __expf(m_r - mnew);
    m_r = mnew;
    float rsum = 0.f;
#pragma unroll
    for (int sf = 0; sf < 4; ++sf)
#pragma unroll
      for (int r = 0; r < 4; ++r) {
        const float p = __expf(scr[sf][r] - mnew);
        scr[sf][r] = p;
        rsum += p;
      }
    rsum += __shfl_xor(rsum, 16, 64);
    rsum += __shfl_xor(rsum, 32, 64);
    l_r = l_r * corr + rsum;
#pragma unroll
    for (int df = 0; df < 4; ++df)
#pragma unroll
      for (int r = 0; r < 4; ++r) oacc[df][r] *= corr;

    // ---- PV: O^T += V^T . P (P packed in-register with matching sigma) ----
#pragma unroll
    for (int c = 0; c < 2; ++c) {
      short8v pb;
#pragma unroll
      for (int e = 0; e < 4; ++e) {
        pb[e] = (short)f2bf(scr[2 * c][e]);
        pb[e + 4] = (short)f2bf(scr[2 * c + 1][e]);
      }
#pragma unroll
      for (int df = 0; df < 4; ++df)
        oacc[df] = __builtin_amdgcn_mfma_f32_16x16x32_bf16(
            ldfragS(Vt, 16 * df + r16, 72, 32 * c, g), pb, oacc[df], 0, 0, 0);
    }
  }

  // ---- epilogue: barrier (Vt reads done), reuse K/V LDS as fp32 scratch ----
  __syncthreads();
  float* scr2 = reinterpret_cast<float*>(SM) + wid * 1088;  // 16x68 per wave
  const float inv = (l_r > 0.f) ? (1.0f / l_r) : 0.f;
#pragma unroll
  for (int df = 0; df < 4; ++df)
#pragma unroll
    for (int r = 0; r < 4; ++r)
      scr2[r16 * 68 + 16 * df + 4 * g + r] = oacc[df][r] * inv;
  asm volatile("s_waitcnt lgkmcnt(0)" ::: "memory");
  __builtin_amdgcn_sched_barrier(0);
  const int orow = lane >> 2;
  const int ocol = (lane & 3) * 16;
  const size_t obase =
      ((size_t)b * SEQ + t0 + wid * 16 + orow) * DIMSZ + h * HEAD_DIM + ocol;
  short8v h0, h1, l0, l1;
#pragma unroll
  for (int i = 0; i < 8; ++i) {
    unsigned short hh, ll;
    split2(scr2[orow * 68 + ocol + i], hh, ll);
    h0[i] = (short)hh; l0[i] = (short)ll;
    split2(scr2[orow * 68 + ocol + 8 + i], hh, ll);
    h1[i] = (short)hh; l1[i] = (short)ll;
  }
  *reinterpret_cast<short8v*>(aoh + obase) = h0;
  *reinterpret_cast<short8v*>(aoh + obase + 8) = h1;
  *reinterpret_cast<short8v*>(aol + obase) = l0;
  *reinterpret_cast<short8v*>(aol + obase + 8) = l1;
}

// ---------------------------------------------------------------------------
extern "C" void kernel_launch(void* const* d_in, const int* in_sizes, int n_in,
                              void* d_out, int out_size, void* d_ws, size_t ws_size,
                              hipStream_t stream) {
  const float* x = (const float*)d_in[0];
  const float* r = (const float*)d_in[1];
  const unsigned char* km = (const unsigned char*)d_in[2];
  const float* Wqkv = (const float*)d_in[3];
  const float* Wr = (const float*)d_in[4];
  const float* u = (const float*)d_in[5];
  const float* v = (const float*)d_in[6];
  const float* Wout = (const float*)d_in[7];
  const float* bout = (const float*)d_in[8];
  float* out = (float*)d_out;

  // workspace layout (bytes); high-water 75,497,472 B (proven)
  char* ws = (char*)d_ws;
  unsigned short* x_hi  = (unsigned short*)(ws + 0);
  unsigned short* x_lo  = (unsigned short*)(ws + 8388608);
  unsigned short* wq_hi = (unsigned short*)(ws + 16777216);
  unsigned short* wq_lo = (unsigned short*)(ws + 23068672);
  unsigned short* wr_hi = (unsigned short*)(ws + 29360128);
  unsigned short* wr_lo = (unsigned short*)(ws + 31457280);
  unsigned short* wo_hi = (unsigned short*)(ws + 33554432);
  unsigned short* wo_lo = (unsigned short*)(ws + 35651584);
  unsigned short* qbf   = (unsigned short*)(ws + 37748736);
  unsigned short* kbf   = (unsigned short*)(ws + 46137344);
  unsigned short* vtb   = (unsigned short*)(ws + 54525952);
  unsigned short* rrbf  = (unsigned short*)(ws + 62914560);
  unsigned short* r_hi  = (unsigned short*)(ws + 67108864);
  unsigned short* r_lo  = (unsigned short*)(ws + 71303168);
  unsigned short* ao_hi = x_hi;  // x planes dead after qkv GEMM
  unsigned short* ao_lo = x_lo;

  k_conv_split<<<2048, 256, 0, stream>>>(x, x_hi, x_lo, (BATCH * SEQ * DIMSZ) / 4);
  k_conv_split<<<2048, 256, 0, stream>>>(r, r_hi, r_lo, (SEQ * DIMSZ) / 4);
  k_conv_wT<<<dim3(12, 64), 256, 0, stream>>>(Wqkv, wq_hi, wq_lo, 3 * DIMSZ);
  k_conv_wT<<<dim3(4, 64), 256, 0, stream>>>(Wr, wr_hi, wr_lo, DIMSZ);
  k_conv_wT<<<dim3(4, 64), 256, 0, stream>>>(Wout, wo_hi, wo_lo, DIMSZ);

  k_gemm_bf_qkv<<<dim3(24, 32), 256, 0, stream>>>(x_hi, x_lo, wq_hi, wq_lo, qbf, kbf, vtb);
  k_gemm_bf_r<<<dim3(8, 16), 256, 0, stream>>>(r_hi, r_lo, wr_hi, wr_lo, rrbf);
  k_attn_mfma<<<dim3(1024), 256, 0, stream>>>(qbf, kbf, vtb, rrbf, u, v, km, ao_hi, ao_lo);
  k_gemm_bf_out<<<dim3(8, 32), 256, 0, stream>>>(ao_hi, ao_lo, wo_hi, wo_lo, bout, out);
}

// Round 11
// 349.534 us; speedup vs baseline: 6.2455x; 1.1118x over previous
//
#include <hip/hip_runtime.h>
#include <hip/hip_bf16.h>

#define DIMSZ 1024
#define HEADS 16
#define HEAD_DIM 64
#define BATCH 2
#define SEQ 2048
#define KDIM 1024

typedef __attribute__((ext_vector_type(4))) short short4v;
typedef __attribute__((ext_vector_type(8))) short short8v;
typedef __attribute__((ext_vector_type(4))) float f32x4;

__device__ __forceinline__ unsigned short f2bf(float f) {
  unsigned int u = __float_as_uint(f);
  u += 0x7fffu + ((u >> 16) & 1u);
  return (unsigned short)(u >> 16);
}
__device__ __forceinline__ float bf2f(unsigned short h) {
  return __uint_as_float(((unsigned int)h) << 16);
}
__device__ __forceinline__ void split2(float f, unsigned short& h, unsigned short& l) {
  h = f2bf(f);
  l = f2bf(f - bf2f(h));
}

// Fragment load with sigma mapping: element e (k-group g) holds
// k = k0 + 4g + (e&3) + 16*(e>>2). Same permutation for A, B and P operands,
// so the contraction is invariant to the HW k-mapping (proven round 3).
__device__ __forceinline__ short8v ldfragS(const unsigned short* base, int row, int stride,
                                           int k0, int g) {
  const short4v lo = *reinterpret_cast<const short4v*>(base + row * stride + k0 + 4 * g);
  const short4v hi = *reinterpret_cast<const short4v*>(base + row * stride + k0 + 16 + 4 * g);
  return __builtin_shufflevector(lo, hi, 0, 1, 2, 3, 4, 5, 6, 7);
}

// ---------------------------------------------------------------------------
// Conversion: fp32 -> bf16 (single plane; A-side operands)
// ---------------------------------------------------------------------------
__global__ __launch_bounds__(256) void k_conv_bf(const float* __restrict__ in,
                                                 unsigned short* __restrict__ hi,
                                                 int n4) {
  int idx = blockIdx.x * 256 + threadIdx.x;
  const int stride = gridDim.x * 256;
  for (; idx < n4; idx += stride) {
    const float4 f = reinterpret_cast<const float4*>(in)[idx];
    short4v h4;
    h4[0] = (short)f2bf(f.x);
    h4[1] = (short)f2bf(f.y);
    h4[2] = (short)f2bf(f.z);
    h4[3] = (short)f2bf(f.w);
    reinterpret_cast<short4v*>(hi)[idx] = h4;
  }
}

// ---------------------------------------------------------------------------
// Conversion: W [KDIM][N] fp32 -> transposed (hi, lo) planes [N][KDIM] bf16
// ---------------------------------------------------------------------------
__global__ __launch_bounds__(256) void k_conv_wT(const float* __restrict__ W,
                                                 unsigned short* __restrict__ th,
                                                 unsigned short* __restrict__ tl,
                                                 int N) {
  const int n = blockIdx.x * 256 + threadIdx.x;
  const int k0 = blockIdx.y * 16;
  unsigned short h16[16], l16[16];
#pragma unroll
  for (int i = 0; i < 16; ++i)
    split2(W[(size_t)(k0 + i) * N + n], h16[i], l16[i]);
  short8v o;
  unsigned short* dh = th + (size_t)n * KDIM + k0;
  unsigned short* dl = tl + (size_t)n * KDIM + k0;
#pragma unroll
  for (int i = 0; i < 8; ++i) o[i] = (short)h16[i];
  *reinterpret_cast<short8v*>(dh) = o;
#pragma unroll
  for (int i = 0; i < 8; ++i) o[i] = (short)h16[8 + i];
  *reinterpret_cast<short8v*>(dh + 8) = o;
#pragma unroll
  for (int i = 0; i < 8; ++i) o[i] = (short)l16[i];
  *reinterpret_cast<short8v*>(dl) = o;
#pragma unroll
  for (int i = 0; i < 8; ++i) o[i] = (short)l16[8 + i];
  *reinterpret_cast<short8v*>(dl + 8) = o;
}

// ---------------------------------------------------------------------------
// 2-term split GEMM core: A bf16 single plane, B = (hi, lo) pre-transposed.
//   acc += Ah*Bh + Ah*Bl   (A-side low bits dropped: consumers round through
//   bf16 anyway, so the added 2^-9-class error matches existing rounding.)
// 128x128 tile, BK=32, 4 waves (2x2), 64x64/wave. LDS 3 planes of [128][40]
// shorts = 30.7 KB -> 5 blocks/CU (was 4 at 41 KB).
// ---------------------------------------------------------------------------
__device__ __forceinline__ void gemm2_core(const unsigned short* __restrict__ Ah,
                                           const unsigned short* __restrict__ Bh,
                                           const unsigned short* __restrict__ Bl,
                                           int m0, int n0, unsigned short* sm,
                                           f32x4 acc[4][4]) {
  unsigned short* sAh = sm;
  unsigned short* sBh = sm + 5120;
  unsigned short* sBl = sm + 10240;
  const int tid = threadIdx.x;
  const int lane = tid & 63, wid = tid >> 6;
  const int g = lane >> 4, r16 = lane & 15;
  const int wm = wid >> 1, wn = wid & 1;
  const int srow = tid >> 1, sh16 = (tid & 1) * 16;
  const size_t aoff = (size_t)(m0 + srow) * KDIM + sh16;
  const size_t boff = (size_t)(n0 + srow) * KDIM + sh16;
  const int sws = srow * 40 + sh16;

  short8v ah0 = *reinterpret_cast<const short8v*>(Ah + aoff);
  short8v ah1 = *reinterpret_cast<const short8v*>(Ah + aoff + 8);
  short8v bh0 = *reinterpret_cast<const short8v*>(Bh + boff);
  short8v bh1 = *reinterpret_cast<const short8v*>(Bh + boff + 8);
  short8v bl0 = *reinterpret_cast<const short8v*>(Bl + boff);
  short8v bl1 = *reinterpret_cast<const short8v*>(Bl + boff + 8);

  for (int k0 = 0; k0 < KDIM; k0 += 32) {
    __syncthreads();
    *reinterpret_cast<short8v*>(sAh + sws) = ah0;
    *reinterpret_cast<short8v*>(sAh + sws + 8) = ah1;
    *reinterpret_cast<short8v*>(sBh + sws) = bh0;
    *reinterpret_cast<short8v*>(sBh + sws + 8) = bh1;
    *reinterpret_cast<short8v*>(sBl + sws) = bl0;
    *reinterpret_cast<short8v*>(sBl + sws + 8) = bl1;
    __syncthreads();
    if (k0 + 32 < KDIM) {  // prefetch next tile under this tile's MFMA
      ah0 = *reinterpret_cast<const short8v*>(Ah + aoff + k0 + 32);
      ah1 = *reinterpret_cast<const short8v*>(Ah + aoff + k0 + 40);
      bh0 = *reinterpret_cast<const short8v*>(Bh + boff + k0 + 32);
      bh1 = *reinterpret_cast<const short8v*>(Bh + boff + k0 + 40);
      bl0 = *reinterpret_cast<const short8v*>(Bl + boff + k0 + 32);
      bl1 = *reinterpret_cast<const short8v*>(Bl + boff + k0 + 40);
    }
    short8v fah[4], fbh[4], fbl[4];
#pragma unroll
    for (int i = 0; i < 4; ++i) {
      fah[i] = ldfragS(sAh, wm * 64 + i * 16 + r16, 40, 0, g);
      fbh[i] = ldfragS(sBh, wn * 64 + i * 16 + r16, 40, 0, g);
      fbl[i] = ldfragS(sBl, wn * 64 + i * 16 + r16, 40, 0, g);
    }
#pragma unroll
    for (int mf = 0; mf < 4; ++mf)
#pragma unroll
      for (int nf = 0; nf < 4; ++nf) {
        acc[mf][nf] = __builtin_amdgcn_mfma_f32_16x16x32_bf16(fah[mf], fbh[nf], acc[mf][nf], 0, 0, 0);
        acc[mf][nf] = __builtin_amdgcn_mfma_f32_16x16x32_bf16(fah[mf], fbl[nf], acc[mf][nf], 0, 0, 0);
      }
  }
  __syncthreads();  // LDS free for epilogue scratch reuse
}

#define GEMM_PROLOG                                        \
  __shared__ __align__(16) unsigned short sm[15360];       \
  f32x4 acc[4][4];                                         \
  _Pragma("unroll") for (int i = 0; i < 4; ++i)            \
      _Pragma("unroll") for (int j = 0; j < 4; ++j)        \
          acc[i][j] = (f32x4){0.f, 0.f, 0.f, 0.f};         \
  const int n0 = blockIdx.x * 128;                         \
  const int m0 = blockIdx.y * 128;                         \
  const int tid = threadIdx.x;                             \
  const int lane = tid & 63, wid = tid >> 6;               \
  const int g = lane >> 4, r16 = lane & 15;                \
  const int wm = wid >> 1, wn = wid & 1;

// ---------------------------------------------------------------------------
// qkv GEMM: A = x bf16, B = Wqkv^T (hi,lo). Outputs q,k bf16 [bh][t][d],
// v bf16 [bh][d][t] (transposed stores).
// ---------------------------------------------------------------------------
__global__ __launch_bounds__(256) void k_gemm_bf_qkv(
    const unsigned short* __restrict__ Xh,
    const unsigned short* __restrict__ Wh, const unsigned short* __restrict__ Wl,
    unsigned short* __restrict__ qbf, unsigned short* __restrict__ kbf,
    unsigned short* __restrict__ vtb) {
  GEMM_PROLOG
  gemm2_core(Xh, Wh, Wl, m0, n0, sm, acc);

  const int n_w = n0 + wn * 64;
  const int comp = n_w >> 10;
  const int h = (n_w >> 6) & 15;
  if (comp == 2) {
#pragma unroll
    for (int mf = 0; mf < 4; ++mf) {
      const int m = m0 + wm * 64 + mf * 16 + 4 * g;
      const int b = m >> 11, t = m & (SEQ - 1);
#pragma unroll
      for (int nf = 0; nf < 4; ++nf) {
        const int d = nf * 16 + r16;
        short4v p;
#pragma unroll
        for (int r = 0; r < 4; ++r) p[r] = (short)f2bf(acc[mf][nf][r]);
        *reinterpret_cast<short4v*>(
            vtb + ((size_t)(b * HEADS + h) * HEAD_DIM + d) * SEQ + t) = p;
      }
    }
  } else {
    unsigned short* dst = comp ? kbf : qbf;
    float* scr = reinterpret_cast<float*>(sm) + wid * 1088;  // per-wave 16x68
    const int rr_ = lane >> 2, cc = (lane & 3) * 16;
    for (int mf = 0; mf < 4; ++mf) {
#pragma unroll
      for (int nf = 0; nf < 4; ++nf)
#pragma unroll
        for (int r = 0; r < 4; ++r)
          scr[(4 * g + r) * 68 + nf * 16 + r16] = acc[mf][nf][r];
      asm volatile("s_waitcnt lgkmcnt(0)" ::: "memory");
      __builtin_amdgcn_sched_barrier(0);
      const int m = m0 + wm * 64 + mf * 16 + rr_;
      const int b = m >> 11, t = m & (SEQ - 1);
      unsigned short* drow = dst + ((size_t)(b * HEADS + h) * SEQ + t) * HEAD_DIM + cc;
      short8v o0, o1;
#pragma unroll
      for (int i = 0; i < 8; ++i) {
        o0[i] = (short)f2bf(scr[rr_ * 68 + cc + i]);
        o1[i] = (short)f2bf(scr[rr_ * 68 + cc + 8 + i]);
      }
      *reinterpret_cast<short8v*>(drow) = o0;
      *reinterpret_cast<short8v*>(drow + 8) = o1;
      asm volatile("s_waitcnt lgkmcnt(0)" ::: "memory");
      __builtin_amdgcn_sched_barrier(0);
    }
  }
}

// ---------------------------------------------------------------------------
// r GEMM: rr bf16 [h][rel][d], rel = 2047 - s (reversed)
// ---------------------------------------------------------------------------
__global__ __launch_bounds__(256) void k_gemm_bf_r(
    const unsigned short* __restrict__ Rh,
    const unsigned short* __restrict__ Wh, const unsigned short* __restrict__ Wl,
    unsigned short* __restrict__ rrbf) {
  GEMM_PROLOG
  gemm2_core(Rh, Wh, Wl, m0, n0, sm, acc);

  const int n_w = n0 + wn * 64;
  const int h = n_w >> 6;
  float* scr = reinterpret_cast<float*>(sm) + wid * 1088;
  const int rr_ = lane >> 2, cc = (lane & 3) * 16;
  for (int mf = 0; mf < 4; ++mf) {
#pragma unroll
    for (int nf = 0; nf < 4; ++nf)
#pragma unroll
      for (int r = 0; r < 4; ++r)
        scr[(4 * g + r) * 68 + nf * 16 + r16] = acc[mf][nf][r];
    asm volatile("s_waitcnt lgkmcnt(0)" ::: "memory");
    __builtin_amdgcn_sched_barrier(0);
    const int s = m0 + wm * 64 + mf * 16 + rr_;
    const int rel = (SEQ - 1) - s;
    unsigned short* drow = rrbf + ((size_t)h * SEQ + rel) * HEAD_DIM + cc;
    short8v o0, o1;
#pragma unroll
    for (int i = 0; i < 8; ++i) {
      o0[i] = (short)f2bf(scr[rr_ * 68 + cc + i]);
      o1[i] = (short)f2bf(scr[rr_ * 68 + cc + 8 + i]);
    }
    *reinterpret_cast<short8v*>(drow) = o0;
    *reinterpret_cast<short8v*>(drow + 8) = o1;
    asm volatile("s_waitcnt lgkmcnt(0)" ::: "memory");
    __builtin_amdgcn_sched_barrier(0);
  }
}

// ---------------------------------------------------------------------------
// out GEMM: A = ao bf16, B = Wout^T (hi,lo), + bias -> fp32 out
// ---------------------------------------------------------------------------
__global__ __launch_bounds__(256) void k_gemm_bf_out(
    const unsigned short* __restrict__ Ah,
    const unsigned short* __restrict__ Wh, const unsigned short* __restrict__ Wl,
    const float* __restrict__ bout, float* __restrict__ out) {
  GEMM_PROLOG
  gemm2_core(Ah, Wh, Wl, m0, n0, sm, acc);

  const int n_w = n0 + wn * 64;
  float* scr = reinterpret_cast<float*>(sm) + wid * 1088;
  const int rr_ = lane >> 2, cc = (lane & 3) * 16;
  for (int mf = 0; mf < 4; ++mf) {
#pragma unroll
    for (int nf = 0; nf < 4; ++nf)
#pragma unroll
      for (int r = 0; r < 4; ++r)
        scr[(4 * g + r) * 68 + nf * 16 + r16] = acc[mf][nf][r];
    asm volatile("s_waitcnt lgkmcnt(0)" ::: "memory");
    __builtin_amdgcn_sched_barrier(0);
    const int m = m0 + wm * 64 + mf * 16 + rr_;
    float* orow = out + (size_t)m * DIMSZ + n_w + cc;
#pragma unroll
    for (int c4 = 0; c4 < 4; ++c4) {
      const float4 bias = *reinterpret_cast<const float4*>(&bout[n_w + cc + 4 * c4]);
      float4 o;
      o.x = scr[rr_ * 68 + cc + 4 * c4 + 0] + bias.x;
      o.y = scr[rr_ * 68 + cc + 4 * c4 + 1] + bias.y;
      o.z = scr[rr_ * 68 + cc + 4 * c4 + 2] + bias.z;
      o.w = scr[rr_ * 68 + cc + 4 * c4 + 3] + bias.w;
      *reinterpret_cast<float4*>(orow + 4 * c4) = o;
    }
    asm volatile("s_waitcnt lgkmcnt(0)" ::: "memory");
    __builtin_amdgcn_sched_barrier(0);
  }
}

// ---------------------------------------------------------------------------
// MFMA flash attention v4 (round-10 proven: T1 XCD remap + T14 + 48.6 KB LDS).
// Epilogue now emits ao as SINGLE bf16 plane (2-term out-GEMM consumes it).
// ---------------------------------------------------------------------------
__global__ __launch_bounds__(256) void k_attn_mfma(const unsigned short* __restrict__ qbf,
                                                   const unsigned short* __restrict__ kbf,
                                                   const unsigned short* __restrict__ vtb,
                                                   const unsigned short* __restrict__ rrbf,
                                                   const float* __restrict__ uu,
                                                   const float* __restrict__ vv,
                                                   const unsigned char* __restrict__ kmask,
                                                   unsigned short* __restrict__ aoh) {
  // packed LDS: Kl[64][72] | Vt[64][72] | RRl[128][72] | GwH 4x[80][18] | KMl[64]f
  __shared__ __align__(16) unsigned short SM[24320];  // 48640 B
  unsigned short* Kl  = SM;
  unsigned short* Vt  = SM + 4608;
  unsigned short* RRl = SM + 9216;
  float* KMl = reinterpret_cast<float*>(SM + 24192);

  const int tid = threadIdx.x;
  const int wid = tid >> 6;
  const int lane = tid & 63;
  const int g = lane >> 4;
  const int r16 = lane & 15;
  // T1 remap: xcd group = wgid % 8 owns bh in [4*xg, 4*xg+4); qt descending.
  const int raw = blockIdx.x;
  const int xg = raw & 7;
  const int idx = raw >> 3;          // 0..127
  const int bh = xg * 4 + (idx & 3);
  const int qt = 31 - (idx >> 2);
  const int b = bh >> 4, h = bh & 15;
  const int t0 = qt * 64;
  unsigned short* GwH = SM + 18432 + wid * 1440;  // per-wave [80][18] bf16

  const unsigned short* kbase = kbf + (size_t)bh * SEQ * HEAD_DIM;
  const unsigned short* vbase = vtb + (size_t)bh * HEAD_DIM * SEQ;
  const unsigned short* rbase = rrbf + (size_t)h * SEQ * HEAD_DIM;

  // staging geometry (constant across tiles)
  const int row = tid >> 2;            // K: s-row / V: d-row
  const int c16 = (tid & 3) << 4;
  const int jr = tid >> 1;             // RR row
  const int ch = (tid & 1) << 5;

  // ---- hoist Q fragments, adding u and v in fp32 ----
  short8v qu[2], qv[2];
  {
    const unsigned short* qrow = qbf + ((size_t)bh * SEQ + t0 + wid * 16 + r16) * HEAD_DIM;
#pragma unroll
    for (int ks = 0; ks < 2; ++ks) {
      const int d0 = 32 * ks + 4 * g;
      const short4v qlo = *reinterpret_cast<const short4v*>(qrow + d0);
      const short4v qhi = *reinterpret_cast<const short4v*>(qrow + d0 + 16);
      const float4 ul = *reinterpret_cast<const float4*>(uu + h * HEAD_DIM + d0);
      const float4 uh = *reinterpret_cast<const float4*>(uu + h * HEAD_DIM + d0 + 16);
      const float4 wl = *reinterpret_cast<const float4*>(vv + h * HEAD_DIM + d0);
      const float4 wh = *reinterpret_cast<const float4*>(vv + h * HEAD_DIM + d0 + 16);
      const float ua[8] = {ul.x, ul.y, ul.z, ul.w, uh.x, uh.y, uh.z, uh.w};
      const float wa[8] = {wl.x, wl.y, wl.z, wl.w, wh.x, wh.y, wh.z, wh.w};
      short8v a, c;
#pragma unroll
      for (int e = 0; e < 4; ++e) {
        const float flo = bf2f((unsigned short)qlo[e]);
        const float fhi = bf2f((unsigned short)qhi[e]);
        a[e] = (short)f2bf(flo + ua[e]);
        a[e + 4] = (short)f2bf(fhi + ua[e + 4]);
        c[e] = (short)f2bf(flo + wa[e]);
        c[e + 4] = (short)f2bf(fhi + wa[e + 4]);
      }
      qu[ks] = a; qv[ks] = c;
    }
  }

  // prefetch registers (named, static — rule #20)
  short8v pK0, pK1, pV0, pV1, pR0, pR1, pR2, pR3;
  unsigned char pM = 0;
  auto LOAD = [&](int st) {
    const int s0 = st * 64;
    const unsigned short* kr = kbase + (size_t)(s0 + row) * HEAD_DIM + c16;
    pK0 = *reinterpret_cast<const short8v*>(kr);
    pK1 = *reinterpret_cast<const short8v*>(kr + 8);
    const unsigned short* vr = vbase + (size_t)row * SEQ + s0 + c16;
    pV0 = *reinterpret_cast<const short8v*>(vr);
    pV1 = *reinterpret_cast<const short8v*>(vr + 8);
    const int rel = (t0 - s0 - 63) + jr;
    if (rel >= 0 && rel < SEQ) {
      const unsigned short* rr = rbase + (size_t)rel * HEAD_DIM + ch;
      pR0 = *reinterpret_cast<const short8v*>(rr);
      pR1 = *reinterpret_cast<const short8v*>(rr + 8);
      pR2 = *reinterpret_cast<const short8v*>(rr + 16);
      pR3 = *reinterpret_cast<const short8v*>(rr + 24);
    } else {
      const short8v z = {};
      pR0 = z; pR1 = z; pR2 = z; pR3 = z;
    }
    if (tid < 64) pM = kmask[(size_t)b * SEQ + s0 + tid];
  };

  f32x4 oacc[4];
#pragma unroll
  for (int df = 0; df < 4; ++df) oacc[df] = (f32x4){0.f, 0.f, 0.f, 0.f};
  float m_r = -1e30f, l_r = 0.f;

  LOAD(0);
  for (int st = 0; st <= qt; ++st) {
    __syncthreads();  // (A) all waves done reading previous tile's LDS

    // ---- write prefetched regs -> LDS (vmcnt wait folds in here) ----
    *reinterpret_cast<short8v*>(&Kl[row * 72 + c16]) = pK0;
    *reinterpret_cast<short8v*>(&Kl[row * 72 + c16 + 8]) = pK1;
    *reinterpret_cast<short8v*>(&Vt[row * 72 + c16]) = pV0;
    *reinterpret_cast<short8v*>(&Vt[row * 72 + c16 + 8]) = pV1;
    *reinterpret_cast<short8v*>(&RRl[jr * 72 + ch]) = pR0;
    *reinterpret_cast<short8v*>(&RRl[jr * 72 + ch + 8]) = pR1;
    *reinterpret_cast<short8v*>(&RRl[jr * 72 + ch + 16]) = pR2;
    *reinterpret_cast<short8v*>(&RRl[jr * 72 + ch + 24]) = pR3;
    if (tid < 64) KMl[tid] = pM ? -1e30f : 0.f;
    __syncthreads();  // (B)

    if (st < qt) LOAD(st + 1);  // T14: loads fly under this tile's compute

    // ---- S^T = K . Qu ----
    f32x4 sacc[4];
#pragma unroll
    for (int sf = 0; sf < 4; ++sf) sacc[sf] = (f32x4){0.f, 0.f, 0.f, 0.f};
#pragma unroll
    for (int sf = 0; sf < 4; ++sf)
#pragma unroll
      for (int ks = 0; ks < 2; ++ks)
        sacc[sf] = __builtin_amdgcn_mfma_f32_16x16x32_bf16(
            ldfragS(Kl, 16 * sf + r16, 72, 32 * ks, g), qu[ks], sacc[sf], 0, 0, 0);

    // ---- G^T = RR . Qv, this wave's 5-fragment j-window (bf16 scratch) ----
#pragma unroll
    for (int fj = 0; fj < 5; ++fj) {
      f32x4 gacc = (f32x4){0.f, 0.f, 0.f, 0.f};
#pragma unroll
      for (int ks = 0; ks < 2; ++ks)
        gacc = __builtin_amdgcn_mfma_f32_16x16x32_bf16(
            ldfragS(RRl, 16 * (wid + fj) + r16, 72, 32 * ks, g), qv[ks], gacc, 0, 0, 0);
#pragma unroll
      for (int r = 0; r < 4; ++r)
        GwH[(16 * fj + 4 * g + r) * 18 + r16] = f2bf(gacc[r]);
    }
    asm volatile("s_waitcnt lgkmcnt(0)" ::: "memory");
    __builtin_amdgcn_sched_barrier(0);

    // ---- diagonal gather + mask + online softmax ----
    float scr[4][4];
    float rmax = -1e30f;
    const int tl = wid * 16 + r16;
    const bool diag = (st == qt);
#pragma unroll
    for (int sf = 0; sf < 4; ++sf) {
#pragma unroll
      for (int r = 0; r < 4; ++r) {
        const int sp = 16 * sf + 4 * g + r;
        const float bd = bf2f(GwH[(63 + r16 - sp) * 18 + r16]);
        float sc = (sacc[sf][r] + bd) * 0.125f + KMl[sp];
        if (diag && sp > tl) sc = -1e30f;
        scr[sf][r] = sc;
        rmax = fmaxf(rmax, sc);
      }
    }
    rmax = fmaxf(rmax, __shfl_xor(rmax, 16, 64));
    rmax = fmaxf(rmax, __shfl_xor(rmax, 32, 64));
    const float mnew = fmaxf(m_r, rmax);
    const float corr = __expf(m_r - mnew);
    m_r = mnew;
    float rsum = 0.f;
#pragma unroll
    for (int sf = 0; sf < 4; ++sf)
#pragma unroll
      for (int r = 0; r < 4; ++r) {
        const float p = __expf(scr[sf][r] - mnew);
        scr[sf][r] = p;
        rsum += p;
      }
    rsum += __shfl_xor(rsum, 16, 64);
    rsum += __shfl_xor(rsum, 32, 64);
    l_r = l_r * corr + rsum;
#pragma unroll
    for (int df = 0; df < 4; ++df)
#pragma unroll
      for (int r = 0; r < 4; ++r) oacc[df][r] *= corr;

    // ---- PV: O^T += V^T . P (P packed in-register with matching sigma) ----
#pragma unroll
    for (int c = 0; c < 2; ++c) {
      short8v pb;
#pragma unroll
      for (int e = 0; e < 4; ++e) {
        pb[e] = (short)f2bf(scr[2 * c][e]);
        pb[e + 4] = (short)f2bf(scr[2 * c + 1][e]);
      }
#pragma unroll
      for (int df = 0; df < 4; ++df)
        oacc[df] = __builtin_amdgcn_mfma_f32_16x16x32_bf16(
            ldfragS(Vt, 16 * df + r16, 72, 32 * c, g), pb, oacc[df], 0, 0, 0);
    }
  }

  // ---- epilogue: barrier (Vt reads done), reuse K/V LDS as fp32 scratch ----
  __syncthreads();
  float* scr2 = reinterpret_cast<float*>(SM) + wid * 1088;  // 16x68 per wave
  const float inv = (l_r > 0.f) ? (1.0f / l_r) : 0.f;
#pragma unroll
  for (int df = 0; df < 4; ++df)
#pragma unroll
    for (int r = 0; r < 4; ++r)
      scr2[r16 * 68 + 16 * df + 4 * g + r] = oacc[df][r] * inv;
  asm volatile("s_waitcnt lgkmcnt(0)" ::: "memory");
  __builtin_amdgcn_sched_barrier(0);
  const int orow = lane >> 2;
  const int ocol = (lane & 3) * 16;
  const size_t obase =
      ((size_t)b * SEQ + t0 + wid * 16 + orow) * DIMSZ + h * HEAD_DIM + ocol;
  short8v h0, h1;
#pragma unroll
  for (int i = 0; i < 8; ++i) {
    h0[i] = (short)f2bf(scr2[orow * 68 + ocol + i]);
    h1[i] = (short)f2bf(scr2[orow * 68 + ocol + 8 + i]);
  }
  *reinterpret_cast<short8v*>(aoh + obase) = h0;
  *reinterpret_cast<short8v*>(aoh + obase + 8) = h1;
}

// ---------------------------------------------------------------------------
extern "C" void kernel_launch(void* const* d_in, const int* in_sizes, int n_in,
                              void* d_out, int out_size, void* d_ws, size_t ws_size,
                              hipStream_t stream) {
  const float* x = (const float*)d_in[0];
  const float* r = (const float*)d_in[1];
  const unsigned char* km = (const unsigned char*)d_in[2];
  const float* Wqkv = (const float*)d_in[3];
  const float* Wr = (const float*)d_in[4];
  const float* u = (const float*)d_in[5];
  const float* v = (const float*)d_in[6];
  const float* Wout = (const float*)d_in[7];
  const float* bout = (const float*)d_in[8];
  float* out = (float*)d_out;

  // workspace layout (bytes); high-water 62,914,560 B (< proven 75.5 MB)
  char* ws = (char*)d_ws;
  unsigned short* x_hi  = (unsigned short*)(ws + 0);         //  8,388,608
  unsigned short* wq_hi = (unsigned short*)(ws + 8388608);   //  6,291,456
  unsigned short* wq_lo = (unsigned short*)(ws + 14680064);  //  6,291,456
  unsigned short* wr_hi = (unsigned short*)(ws + 20971520);  //  2,097,152
  unsigned short* wr_lo = (unsigned short*)(ws + 23068672);  //  2,097,152
  unsigned short* wo_hi = (unsigned short*)(ws + 25165824);  //  2,097,152
  unsigned short* wo_lo = (unsigned short*)(ws + 27262976);  //  2,097,152
  unsigned short* qbf   = (unsigned short*)(ws + 29360128);  //  8,388,608
  unsigned short* kbf   = (unsigned short*)(ws + 37748736);  //  8,388,608
  unsigned short* vtb   = (unsigned short*)(ws + 46137344);  //  8,388,608
  unsigned short* rrbf  = (unsigned short*)(ws + 54525952);  //  4,194,304
  unsigned short* r_hi  = (unsigned short*)(ws + 58720256);  //  4,194,304
  unsigned short* ao_hi = x_hi;  // x plane dead after qkv GEMM

  k_conv_bf<<<1024, 256, 0, stream>>>(x, x_hi, (BATCH * SEQ * DIMSZ) / 4);
  k_conv_bf<<<512, 256, 0, stream>>>(r, r_hi, (SEQ * DIMSZ) / 4);
  k_conv_wT<<<dim3(12, 64), 256, 0, stream>>>(Wqkv, wq_hi, wq_lo, 3 * DIMSZ);
  k_conv_wT<<<dim3(4, 64), 256, 0, stream>>>(Wr, wr_hi, wr_lo, DIMSZ);
  k_conv_wT<<<dim3(4, 64), 256, 0, stream>>>(Wout, wo_hi, wo_lo, DIMSZ);

  k_gemm_bf_qkv<<<dim3(24, 32), 256, 0, stream>>>(x_hi, wq_hi, wq_lo, qbf, kbf, vtb);
  k_gemm_bf_r<<<dim3(8, 16), 256, 0, stream>>>(r_hi, wr_hi, wr_lo, rrbf);
  k_attn_mfma<<<dim3(1024), 256, 0, stream>>>(qbf, kbf, vtb, rrbf, u, v, km, ao_hi);
  k_gemm_bf_out<<<dim3(8, 32), 256, 0, stream>>>(ao_hi, wo_hi, wo_lo, bout, out);
}